// Round 1
// baseline (464.540 us; speedup 1.0000x reference)
//
#include <hip/hip_runtime.h>
#include <math.h>

#define S_LEN 2049
#define P_LEN 2048
#define EMB 512
#define NH 8
#define HD 64
#define QKV_LD 1536
#define WSZ 32
#define WIN 65
#define SCALE 0.125f

__device__ inline float wave_sum64(float v) {
#pragma unroll
  for (int off = 32; off > 0; off >>= 1) v += __shfl_xor(v, off, 64);
  return v;
}

// C[M,N] = A[M,K] @ W[N,K]^T + bias[N]
template <int BM, int BN, int TM, int TN>
__global__ __launch_bounds__(256) void gemm_wt(const float* __restrict__ A,
                                               const float* __restrict__ W,
                                               const float* __restrict__ bias,
                                               float* __restrict__ C,
                                               int M, int N, int K) {
  constexpr int BK = 16;
  __shared__ float As[BK][BM + 4];
  __shared__ float Bs[BK][BN + 4];
  const int m0 = blockIdx.x * BM;
  const int n0 = blockIdx.y * BN;
  const int t = threadIdx.x;
  constexpr int NX = BN / TN;  // threads along n (16)
  const int tx = t % NX;
  const int ty = t / NX;

  float acc[TM][TN];
#pragma unroll
  for (int i = 0; i < TM; i++)
#pragma unroll
    for (int j = 0; j < TN; j++) acc[i][j] = 0.f;

  for (int k0 = 0; k0 < K; k0 += BK) {
    // stage A tile (BM x BK), transposed into As[k][m]
#pragma unroll
    for (int s = t; s < BM * BK / 4; s += 256) {
      int row = s >> 2;
      int kc = (s & 3) << 2;
      float4 v = make_float4(0.f, 0.f, 0.f, 0.f);
      if (m0 + row < M)
        v = *(const float4*)(A + (size_t)(m0 + row) * K + k0 + kc);
      As[kc + 0][row] = v.x;
      As[kc + 1][row] = v.y;
      As[kc + 2][row] = v.z;
      As[kc + 3][row] = v.w;
    }
    // stage W tile (BN x BK), transposed into Bs[k][n]
#pragma unroll
    for (int s = t; s < BN * BK / 4; s += 256) {
      int row = s >> 2;
      int kc = (s & 3) << 2;
      float4 v = *(const float4*)(W + (size_t)(n0 + row) * K + k0 + kc);
      Bs[kc + 0][row] = v.x;
      Bs[kc + 1][row] = v.y;
      Bs[kc + 2][row] = v.z;
      Bs[kc + 3][row] = v.w;
    }
    __syncthreads();
#pragma unroll
    for (int kk = 0; kk < BK; kk++) {
      float a[TM], b[TN];
#pragma unroll
      for (int i = 0; i < TM; i += 4)
        *(float4*)&a[i] = *(const float4*)&As[kk][ty * TM + i];
#pragma unroll
      for (int j = 0; j < TN; j += 4)
        *(float4*)&b[j] = *(const float4*)&Bs[kk][tx * TN + j];
#pragma unroll
      for (int i = 0; i < TM; i++)
#pragma unroll
        for (int j = 0; j < TN; j++) acc[i][j] = fmaf(a[i], b[j], acc[i][j]);
    }
    __syncthreads();
  }

#pragma unroll
  for (int i = 0; i < TM; i++) {
    int m = m0 + ty * TM + i;
    if (m < M) {
#pragma unroll
      for (int j = 0; j < TN; j += 4) {
        int n = n0 + tx * TN + j;
        float4 o;
        o.x = acc[i][j + 0] + bias[n + 0];
        o.y = acc[i][j + 1] + bias[n + 1];
        o.z = acc[i][j + 2] + bias[n + 2];
        o.w = acc[i][j + 3] + bias[n + 3];
        *(float4*)(C + (size_t)m * N + n) = o;
      }
    }
  }
}

// Sliding-window (dilated) attention for patch tokens.
// One wave per query (lane = head dim), online softmax.
__global__ __launch_bounds__(256) void patch_attn(const float* __restrict__ qkv,
                                                  float* __restrict__ attn) {
  const int lane = threadIdx.x & 63;
  const int wv = threadIdx.x >> 6;
  const int CH = P_LEN / 16;  // 128 chunks of 16 queries
  int bid = blockIdx.x;
  int chunk = bid % CH;
  int h = (bid / CH) % NH;
  int b = bid / (CH * NH);

  const float* base = qkv + (size_t)b * S_LEN * QKV_LD;
  const float* kcls = base + 512 + h * HD;  // s = 0 row, k section
  float kcl = kcls[lane];
  float vcl = kcls[512 + lane];

  for (int jj = 0; jj < 4; jj++) {
    int p = chunk * 16 + wv * 4 + jj;
    const float* qrow = base + (size_t)(1 + p) * QKV_LD + h * HD;
    float qd = qrow[lane] * SCALE;

    // cls key first (always valid)
    float m = wave_sum64(qd * kcl);
    float l = 1.0f;
    float o = vcl;

    for (int w = 0; w < WIN; w++) {
      int pos = p + (w - WSZ) * 2;
      if (pos < 0 || pos >= P_LEN) continue;  // wave-uniform branch
      const float* krow = base + (size_t)(1 + pos) * QKV_LD + 512 + h * HD;
      float kv = krow[lane];
      float vv = krow[512 + lane];
      float s = wave_sum64(qd * kv);
      float mn = fmaxf(m, s);
      float c0 = __expf(m - mn);
      float c1 = __expf(s - mn);
      l = l * c0 + c1;
      o = o * c0 + c1 * vv;
      m = mn;
    }
    attn[((size_t)b * S_LEN + 1 + p) * EMB + h * HD + lane] = o / l;
  }
}

// CLS token attends over all S keys. One block (16 waves) per (b,h).
__global__ __launch_bounds__(1024) void cls_attn(const float* __restrict__ qkv,
                                                 float* __restrict__ attn) {
  const int lane = threadIdx.x & 63;
  const int wv = threadIdx.x >> 6;  // 0..15
  int h = blockIdx.x % NH;
  int b = blockIdx.x / NH;
  const float* base = qkv + (size_t)b * S_LEN * QKV_LD;
  float qd = base[h * HD + lane] * SCALE;  // q of s=0

  float m = -1e30f, l = 0.f, o = 0.f;
  for (int j = wv; j < S_LEN; j += 16) {
    const float* krow = base + (size_t)j * QKV_LD + 512 + h * HD;
    float kv = krow[lane];
    float vv = krow[512 + lane];
    float s = wave_sum64(qd * kv);
    float mn = fmaxf(m, s);
    float c0 = __expf(m - mn);
    float c1 = __expf(s - mn);
    l = l * c0 + c1;
    o = o * c0 + c1 * vv;
    m = mn;
  }

  __shared__ float sm[16], sl[16], so[16][64];
  if (lane == 0) {
    sm[wv] = m;
    sl[wv] = l;
  }
  so[wv][lane] = o;
  __syncthreads();
  if (wv == 0) {
    float M = -1e30f;
    for (int i = 0; i < 16; i++) M = fmaxf(M, sm[i]);
    float L = 0.f, O = 0.f;
    for (int i = 0; i < 16; i++) {
      float c = __expf(sm[i] - M);
      L += sl[i] * c;
      O += so[i][lane] * c;
    }
    attn[((size_t)b * S_LEN) * EMB + h * HD + lane] = O / L;
  }
}

extern "C" void kernel_launch(void* const* d_in, const int* in_sizes, int n_in,
                              void* d_out, int out_size, void* d_ws,
                              size_t ws_size, hipStream_t stream) {
  const float* x = (const float*)d_in[0];
  const float* qkv_w = (const float*)d_in[1];
  const float* qkv_b = (const float*)d_in[2];
  const float* out_w = (const float*)d_in[3];
  const float* out_b = (const float*)d_in[4];
  float* out = (float*)d_out;

  float* qkv_buf = (float*)d_ws;                               // 2*2049*1536 f32
  float* attn_buf = qkv_buf + (size_t)2 * S_LEN * QKV_LD;      // 2*2049*512 f32

  const int M = 2 * S_LEN;  // 4098 rows

  // QKV projection: (4098,512) @ (1536,512)^T
  dim3 g1((M + 127) / 128, QKV_LD / 128);
  gemm_wt<128, 128, 8, 8><<<g1, 256, 0, stream>>>(x, qkv_w, qkv_b, qkv_buf, M,
                                                  QKV_LD, EMB);

  cls_attn<<<2 * NH, 1024, 0, stream>>>(qkv_buf, attn_buf);
  patch_attn<<<2 * NH * (P_LEN / 16), 256, 0, stream>>>(qkv_buf, attn_buf);

  // Output projection: (4098,512) @ (512,512)^T
  dim3 g2((M + 127) / 128, EMB / 64);
  gemm_wt<128, 64, 8, 4><<<g2, 256, 0, stream>>>(attn_buf, out_w, out_b, out, M,
                                                 EMB, EMB);
}

// Round 2
// 239.228 us; speedup vs baseline: 1.9418x; 1.9418x over previous
//
#include <hip/hip_runtime.h>
#include <math.h>

#define S_LEN 2049
#define P_LEN 2048
#define EMB 512
#define NH 8
#define HD 64
#define QKV_LD 1536
#define SCALE 0.125f

typedef __bf16 bf16x8 __attribute__((ext_vector_type(8)));
typedef float f32x4 __attribute__((ext_vector_type(4)));
typedef unsigned short u16x8 __attribute__((ext_vector_type(8)));

__device__ inline unsigned short f2bf(float f) {
  unsigned u = __float_as_uint(f);
  u += 0x7fff + ((u >> 16) & 1);  // RNE
  return (unsigned short)(u >> 16);
}
__device__ inline float bf2f(unsigned short h) {
  return __uint_as_float(((unsigned)h) << 16);
}

__device__ inline float wave_sum64(float v) {
#pragma unroll
  for (int off = 32; off > 0; off >>= 1) v += __shfl_xor(v, off, 64);
  return v;
}

// C[M,N] = A[M,K] @ W[N,K]^T + bias, split-bf16 (hi/lo) 3-term MFMA.
// acc = Ah*Wh + Al*Wh + Ah*Wl  (AlWl term ~2^-18, dropped)
template <int BM, int BN>
__global__ __launch_bounds__(256, 2) void gemm_split(
    const float* __restrict__ A, const float* __restrict__ W,
    const float* __restrict__ bias, float* __restrict__ C, int M, int N,
    int K) {
  constexpr int BK = 32;
  constexpr int LDK = BK + 8;  // 40 ushorts = 80 B: 2-way (free) frag reads
  __shared__ unsigned short Ah[BM * LDK], Al[BM * LDK];
  __shared__ unsigned short Wh[BN * LDK], Wl[BN * LDK];

  const int t = threadIdx.x;
  const int lane = t & 63;
  const int wv = t >> 6;
  constexpr int WM = BM / 2, WN = BN / 2;
  constexpr int RM = WM / 16, RN = WN / 16;
  const int wm = wv & 1, wn = wv >> 1;
  const int m0 = blockIdx.x * BM, n0 = blockIdx.y * BN;
  const int lm = lane & 15, lq = lane >> 4;

  f32x4 acc[RM][RN];
#pragma unroll
  for (int i = 0; i < RM; i++)
#pragma unroll
    for (int j = 0; j < RN; j++) acc[i][j] = (f32x4){0.f, 0.f, 0.f, 0.f};

  for (int k0 = 0; k0 < K; k0 += BK) {
    __syncthreads();
    // stage A tile: BM x 32 fp32 -> hi/lo bf16 (8 floats per thread-chunk)
    constexpr int ACH = (BM * BK) / (256 * 8);
#pragma unroll
    for (int c = 0; c < ACH; c++) {
      int idx = c * 256 + t;
      int row = idx >> 2;
      int col = (idx & 3) * 8;
      int gr = m0 + row;
      gr = gr < M ? gr : M - 1;  // clamp (store is guarded)
      const float* g = A + (size_t)gr * K + k0 + col;
      float4 f0 = *(const float4*)g;
      float4 f1 = *(const float4*)(g + 4);
      float ff[8] = {f0.x, f0.y, f0.z, f0.w, f1.x, f1.y, f1.z, f1.w};
      u16x8 vh, vl;
#pragma unroll
      for (int e = 0; e < 8; e++) {
        unsigned short hh = f2bf(ff[e]);
        vh[e] = hh;
        vl[e] = f2bf(ff[e] - bf2f(hh));
      }
      *(u16x8*)&Ah[row * LDK + col] = vh;
      *(u16x8*)&Al[row * LDK + col] = vl;
    }
    // stage W tile: BN x 32
    constexpr int BCH = (BN * BK) / (256 * 8);
#pragma unroll
    for (int c = 0; c < BCH; c++) {
      int idx = c * 256 + t;
      int row = idx >> 2;
      int col = (idx & 3) * 8;
      const float* g = W + (size_t)(n0 + row) * K + k0 + col;
      float4 f0 = *(const float4*)g;
      float4 f1 = *(const float4*)(g + 4);
      float ff[8] = {f0.x, f0.y, f0.z, f0.w, f1.x, f1.y, f1.z, f1.w};
      u16x8 vh, vl;
#pragma unroll
      for (int e = 0; e < 8; e++) {
        unsigned short hh = f2bf(ff[e]);
        vh[e] = hh;
        vl[e] = f2bf(ff[e] - bf2f(hh));
      }
      *(u16x8*)&Wh[row * LDK + col] = vh;
      *(u16x8*)&Wl[row * LDK + col] = vl;
    }
    __syncthreads();

    // fragments: A-frag m=lane&15, k=(lane>>4)*8+j (verified m89/m92 layout)
    bf16x8 fah[RM], fal[RM], fwh[RN], fwl[RN];
#pragma unroll
    for (int mi = 0; mi < RM; mi++) {
      int r = (wm * WM + mi * 16 + lm) * LDK + lq * 8;
      fah[mi] = *(const bf16x8*)&Ah[r];
      fal[mi] = *(const bf16x8*)&Al[r];
    }
#pragma unroll
    for (int ni = 0; ni < RN; ni++) {
      int r = (wn * WN + ni * 16 + lm) * LDK + lq * 8;
      fwh[ni] = *(const bf16x8*)&Wh[r];
      fwl[ni] = *(const bf16x8*)&Wl[r];
    }
#pragma unroll
    for (int mi = 0; mi < RM; mi++)
#pragma unroll
      for (int ni = 0; ni < RN; ni++) {
        acc[mi][ni] = __builtin_amdgcn_mfma_f32_16x16x32_bf16(
            fah[mi], fwh[ni], acc[mi][ni], 0, 0, 0);
        acc[mi][ni] = __builtin_amdgcn_mfma_f32_16x16x32_bf16(
            fal[mi], fwh[ni], acc[mi][ni], 0, 0, 0);
        acc[mi][ni] = __builtin_amdgcn_mfma_f32_16x16x32_bf16(
            fah[mi], fwl[ni], acc[mi][ni], 0, 0, 0);
      }
  }

  // epilogue: C/D layout col=lane&15, row=(lane>>4)*4+reg (verified m89/m91)
#pragma unroll
  for (int ni = 0; ni < RN; ni++) {
    int n = n0 + wn * WN + ni * 16 + lm;
    float bv = bias[n];
#pragma unroll
    for (int mi = 0; mi < RM; mi++) {
#pragma unroll
      for (int r = 0; r < 4; r++) {
        int m = m0 + wm * WM + mi * 16 + lq * 4 + r;
        if (m < M) C[(size_t)m * N + n] = acc[mi][ni][r] + bv;
      }
    }
  }
}

// Parity-compressed sliding-window attention. p = 2*qc+par: in compressed
// coords the dilated window is contiguous [qc-32, qc+32]. Block = 64 queries
// (one parity), stages exactly 128 K rows (bf16) + 128 V rows (fp32) in LDS.
// 4 threads per query, 16 dims each (d = u*32 + dq*8 + r).
__global__ __launch_bounds__(256) void patch_attn2(
    const float* __restrict__ qkv, float* __restrict__ attn) {
  constexpr int LDK = 80;  // ushorts per K row (64+16 pad: 2-way free)
  constexpr int LDV = 72;  // floats per V row (64+8 pad: 2-way free)
  __shared__ unsigned short Ks[128 * LDK];
  __shared__ float Vs[128 * LDV];

  const int t = threadIdx.x;
  const int qb = blockIdx.x;               // 0..15
  const int h = blockIdx.y;                // 0..7
  const int par = blockIdx.z & 1, b = blockIdx.z >> 1;
  const float* base = qkv + (size_t)b * S_LEN * QKV_LD;
  const int qc0 = qb * 64;

  // stage K (bf16) and V (fp32): rows jc in [qc0-32, qc0+96)
  {
    int rr = t >> 4;
    int cc = (t & 15) * 4;
#pragma unroll
    for (int pass = 0; pass < 8; pass++) {
      int r = pass * 16 + rr;
      int jc = qc0 - 32 + r;
      float4 kv = {0, 0, 0, 0}, vv = {0, 0, 0, 0};
      if (jc >= 0 && jc < P_LEN / 2) {
        const float* g =
            base + (size_t)(1 + 2 * jc + par) * QKV_LD + h * HD + cc;
        kv = *(const float4*)(g + 512);
        vv = *(const float4*)(g + 1024);
      }
      unsigned u0 = ((unsigned)f2bf(kv.y) << 16) | f2bf(kv.x);
      unsigned u1 = ((unsigned)f2bf(kv.w) << 16) | f2bf(kv.z);
      *(uint2*)&Ks[r * LDK + cc] = make_uint2(u0, u1);
      *(float4*)&Vs[r * LDV + cc] = vv;
    }
  }

  const int qi = t >> 2;  // query within block
  const int dq = t & 3;   // dim-quarter
  const int p = 2 * (qc0 + qi) + par;
  const float* qg = base + (size_t)(1 + p) * QKV_LD + h * HD;

  float q[16], o[16];
#pragma unroll
  for (int u = 0; u < 2; u++)
#pragma unroll
    for (int c8 = 0; c8 < 2; c8++) {
      float4 f = *(const float4*)(qg + u * 32 + dq * 8 + c8 * 4);
      int e = u * 8 + c8 * 4;
      q[e + 0] = f.x * SCALE;
      q[e + 1] = f.y * SCALE;
      q[e + 2] = f.z * SCALE;
      q[e + 3] = f.w * SCALE;
    }

  // cls key/value first (always valid): init m = s_cls, l = 1, o = v_cls
  const float* kc = base + 512 + h * HD;
  const float* vc = base + 1024 + h * HD;
  float pt = 0.f;
#pragma unroll
  for (int u = 0; u < 2; u++)
#pragma unroll
    for (int c8 = 0; c8 < 2; c8++) {
      float4 kf = *(const float4*)(kc + u * 32 + dq * 8 + c8 * 4);
      int e = u * 8 + c8 * 4;
      pt = fmaf(q[e + 0], kf.x, pt);
      pt = fmaf(q[e + 1], kf.y, pt);
      pt = fmaf(q[e + 2], kf.z, pt);
      pt = fmaf(q[e + 3], kf.w, pt);
    }
  pt += __shfl_xor(pt, 1, 4);
  pt += __shfl_xor(pt, 2, 4);
  float m = pt, l = 1.f;
#pragma unroll
  for (int u = 0; u < 2; u++)
#pragma unroll
    for (int c8 = 0; c8 < 2; c8++) {
      float4 vf = *(const float4*)(vc + u * 32 + dq * 8 + c8 * 4);
      int e = u * 8 + c8 * 4;
      o[e + 0] = vf.x;
      o[e + 1] = vf.y;
      o[e + 2] = vf.z;
      o[e + 3] = vf.w;
    }

  __syncthreads();

  for (int w = 0; w < 65; w++) {
    int jl = qi + w;  // staged row
    uint4 k0 = *(const uint4*)&Ks[jl * LDK + dq * 8];
    uint4 k1 = *(const uint4*)&Ks[jl * LDK + 32 + dq * 8];
    float s = 0.f;
    unsigned kw[8] = {k0.x, k0.y, k0.z, k0.w, k1.x, k1.y, k1.z, k1.w};
#pragma unroll
    for (int i = 0; i < 8; i++) {
      int e = (i >> 2) * 8 + (i & 3) * 2;
      s = fmaf(q[e + 0], __uint_as_float(kw[i] << 16), s);
      s = fmaf(q[e + 1], __uint_as_float(kw[i] & 0xffff0000u), s);
    }
    s += __shfl_xor(s, 1, 4);
    s += __shfl_xor(s, 2, 4);
    bool valid = (unsigned)(qc0 - 32 + jl) < (unsigned)(P_LEN / 2);
    if (valid) {
      float mn = fmaxf(m, s);
      float c0 = __expf(m - mn);
      float c1 = __expf(s - mn);
      l = l * c0 + c1;
      m = mn;
      const float* vr = &Vs[jl * LDV];
#pragma unroll
      for (int u = 0; u < 2; u++)
#pragma unroll
        for (int c8 = 0; c8 < 2; c8++) {
          float4 vf = *(const float4*)(vr + u * 32 + dq * 8 + c8 * 4);
          int e = u * 8 + c8 * 4;
          o[e + 0] = fmaf(c1, vf.x, o[e + 0] * c0);
          o[e + 1] = fmaf(c1, vf.y, o[e + 1] * c0);
          o[e + 2] = fmaf(c1, vf.z, o[e + 2] * c0);
          o[e + 3] = fmaf(c1, vf.w, o[e + 3] * c0);
        }
    }
  }

  float inv = 1.f / l;
  float* og = attn + ((size_t)b * S_LEN + 1 + p) * EMB + h * HD;
#pragma unroll
  for (int u = 0; u < 2; u++)
#pragma unroll
    for (int c8 = 0; c8 < 2; c8++) {
      int e = u * 8 + c8 * 4;
      float4 f = {o[e + 0] * inv, o[e + 1] * inv, o[e + 2] * inv,
                  o[e + 3] * inv};
      *(float4*)(og + u * 32 + dq * 8 + c8 * 4) = f;
    }
}

// CLS token attends over all S keys. One block (16 waves) per (b,h).
__global__ __launch_bounds__(1024) void cls_attn(const float* __restrict__ qkv,
                                                 float* __restrict__ attn) {
  const int lane = threadIdx.x & 63;
  const int wv = threadIdx.x >> 6;  // 0..15
  int h = blockIdx.x % NH;
  int b = blockIdx.x / NH;
  const float* base = qkv + (size_t)b * S_LEN * QKV_LD;
  float qd = base[h * HD + lane] * SCALE;

  float m = -1e30f, l = 0.f, o = 0.f;
  for (int j = wv; j < S_LEN; j += 16) {
    const float* krow = base + (size_t)j * QKV_LD + 512 + h * HD;
    float kv = krow[lane];
    float vv = krow[512 + lane];
    float s = wave_sum64(qd * kv);
    float mn = fmaxf(m, s);
    float c0 = __expf(m - mn);
    float c1 = __expf(s - mn);
    l = l * c0 + c1;
    o = o * c0 + c1 * vv;
    m = mn;
  }

  __shared__ float sm[16], sl[16], so[16][64];
  if (lane == 0) {
    sm[wv] = m;
    sl[wv] = l;
  }
  so[wv][lane] = o;
  __syncthreads();
  if (wv == 0) {
    float M = -1e30f;
    for (int i = 0; i < 16; i++) M = fmaxf(M, sm[i]);
    float L = 0.f, O = 0.f;
    for (int i = 0; i < 16; i++) {
      float c = __expf(sm[i] - M);
      L += sl[i] * c;
      O += so[i][lane] * c;
    }
    attn[((size_t)b * S_LEN) * EMB + h * HD + lane] = O / L;
  }
}

extern "C" void kernel_launch(void* const* d_in, const int* in_sizes, int n_in,
                              void* d_out, int out_size, void* d_ws,
                              size_t ws_size, hipStream_t stream) {
  const float* x = (const float*)d_in[0];
  const float* qkv_w = (const float*)d_in[1];
  const float* qkv_b = (const float*)d_in[2];
  const float* out_w = (const float*)d_in[3];
  const float* out_b = (const float*)d_in[4];
  float* out = (float*)d_out;

  float* qkv_buf = (float*)d_ws;                           // 2*2049*1536 f32
  float* attn_buf = qkv_buf + (size_t)2 * S_LEN * QKV_LD;  // 2*2049*512 f32

  const int M = 2 * S_LEN;  // 4098

  dim3 gq((M + 127) / 128, QKV_LD / 128);  // 33 x 12
  gemm_split<128, 128><<<gq, 256, 0, stream>>>(x, qkv_w, qkv_b, qkv_buf, M,
                                               QKV_LD, EMB);

  cls_attn<<<2 * NH, 1024, 0, stream>>>(qkv_buf, attn_buf);
  patch_attn2<<<dim3(16, NH, 4), 256, 0, stream>>>(qkv_buf, attn_buf);

  dim3 go((M + 127) / 128, EMB / 64);  // 33 x 8
  gemm_split<128, 64><<<go, 256, 0, stream>>>(attn_buf, out_w, out_b, out, M,
                                              EMB, EMB);
}

// Round 3
// 184.864 us; speedup vs baseline: 2.5129x; 1.2941x over previous
//
#include <hip/hip_runtime.h>
#include <math.h>

#define S_LEN 2049
#define P_LEN 2048
#define EMB 512
#define NH 8
#define HD 64
#define QKV_LD 1536
#define SCALE 0.125f

typedef __bf16 bf16x8 __attribute__((ext_vector_type(8)));
typedef float f32x4 __attribute__((ext_vector_type(4)));
typedef unsigned short u16x8 __attribute__((ext_vector_type(8)));

__device__ inline unsigned short f2bf(float f) {
  unsigned u = __float_as_uint(f);
  u += 0x7fff + ((u >> 16) & 1);  // RNE
  return (unsigned short)(u >> 16);
}
__device__ inline float bf2f(unsigned short h) {
  return __uint_as_float(((unsigned)h) << 16);
}

__device__ inline float wave_sum64(float v) {
#pragma unroll
  for (int off = 32; off > 0; off >>= 1) v += __shfl_xor(v, off, 64);
  return v;
}

// C[M,N] = A[M,K] @ W[N,K]^T + bias, split-bf16 (hi/lo) 3-term MFMA.
// acc = Ah*Wh + Al*Wh + Ah*Wl  (AlWl term ~2^-18, dropped)
template <int BM, int BN>
__global__ __launch_bounds__(256, 2) void gemm_split(
    const float* __restrict__ A, const float* __restrict__ W,
    const float* __restrict__ bias, float* __restrict__ C, int M, int N,
    int K) {
  constexpr int BK = 32;
  constexpr int LDK = BK + 8;  // 40 ushorts = 80 B: 2-way (free) frag reads
  __shared__ unsigned short Ah[BM * LDK], Al[BM * LDK];
  __shared__ unsigned short Wh[BN * LDK], Wl[BN * LDK];

  const int t = threadIdx.x;
  const int lane = t & 63;
  const int wv = t >> 6;
  constexpr int WM = BM / 2, WN = BN / 2;
  constexpr int RM = WM / 16, RN = WN / 16;
  const int wm = wv & 1, wn = wv >> 1;
  const int m0 = blockIdx.x * BM, n0 = blockIdx.y * BN;
  const int lm = lane & 15, lq = lane >> 4;

  f32x4 acc[RM][RN];
#pragma unroll
  for (int i = 0; i < RM; i++)
#pragma unroll
    for (int j = 0; j < RN; j++) acc[i][j] = (f32x4){0.f, 0.f, 0.f, 0.f};

  for (int k0 = 0; k0 < K; k0 += BK) {
    __syncthreads();
    // stage A tile: BM x 32 fp32 -> hi/lo bf16 (8 floats per thread-chunk)
    constexpr int ACH = (BM * BK) / (256 * 8);
#pragma unroll
    for (int c = 0; c < ACH; c++) {
      int idx = c * 256 + t;
      int row = idx >> 2;
      int col = (idx & 3) * 8;
      int gr = m0 + row;
      gr = gr < M ? gr : M - 1;  // clamp (store is guarded)
      const float* g = A + (size_t)gr * K + k0 + col;
      float4 f0 = *(const float4*)g;
      float4 f1 = *(const float4*)(g + 4);
      float ff[8] = {f0.x, f0.y, f0.z, f0.w, f1.x, f1.y, f1.z, f1.w};
      u16x8 vh, vl;
#pragma unroll
      for (int e = 0; e < 8; e++) {
        unsigned short hh = f2bf(ff[e]);
        vh[e] = hh;
        vl[e] = f2bf(ff[e] - bf2f(hh));
      }
      *(u16x8*)&Ah[row * LDK + col] = vh;
      *(u16x8*)&Al[row * LDK + col] = vl;
    }
    // stage W tile: BN x 32
    constexpr int BCH = (BN * BK) / (256 * 8);
#pragma unroll
    for (int c = 0; c < BCH; c++) {
      int idx = c * 256 + t;
      int row = idx >> 2;
      int col = (idx & 3) * 8;
      const float* g = W + (size_t)(n0 + row) * K + k0 + col;
      float4 f0 = *(const float4*)g;
      float4 f1 = *(const float4*)(g + 4);
      float ff[8] = {f0.x, f0.y, f0.z, f0.w, f1.x, f1.y, f1.z, f1.w};
      u16x8 vh, vl;
#pragma unroll
      for (int e = 0; e < 8; e++) {
        unsigned short hh = f2bf(ff[e]);
        vh[e] = hh;
        vl[e] = f2bf(ff[e] - bf2f(hh));
      }
      *(u16x8*)&Wh[row * LDK + col] = vh;
      *(u16x8*)&Wl[row * LDK + col] = vl;
    }
    __syncthreads();

    // fragments: A-frag m=lane&15, k=(lane>>4)*8+j (verified m89/m92 layout)
    bf16x8 fah[RM], fal[RM], fwh[RN], fwl[RN];
#pragma unroll
    for (int mi = 0; mi < RM; mi++) {
      int r = (wm * WM + mi * 16 + lm) * LDK + lq * 8;
      fah[mi] = *(const bf16x8*)&Ah[r];
      fal[mi] = *(const bf16x8*)&Al[r];
    }
#pragma unroll
    for (int ni = 0; ni < RN; ni++) {
      int r = (wn * WN + ni * 16 + lm) * LDK + lq * 8;
      fwh[ni] = *(const bf16x8*)&Wh[r];
      fwl[ni] = *(const bf16x8*)&Wl[r];
    }
#pragma unroll
    for (int mi = 0; mi < RM; mi++)
#pragma unroll
      for (int ni = 0; ni < RN; ni++) {
        acc[mi][ni] = __builtin_amdgcn_mfma_f32_16x16x32_bf16(
            fah[mi], fwh[ni], acc[mi][ni], 0, 0, 0);
        acc[mi][ni] = __builtin_amdgcn_mfma_f32_16x16x32_bf16(
            fal[mi], fwh[ni], acc[mi][ni], 0, 0, 0);
        acc[mi][ni] = __builtin_amdgcn_mfma_f32_16x16x32_bf16(
            fah[mi], fwl[ni], acc[mi][ni], 0, 0, 0);
      }
  }

  // epilogue: C/D layout col=lane&15, row=(lane>>4)*4+reg (verified m89/m91)
#pragma unroll
  for (int ni = 0; ni < RN; ni++) {
    int n = n0 + wn * WN + ni * 16 + lm;
    float bv = bias[n];
#pragma unroll
    for (int mi = 0; mi < RM; mi++) {
#pragma unroll
      for (int r = 0; r < 4; r++) {
        int m = m0 + wm * WM + mi * 16 + lq * 4 + r;
        if (m < M) C[(size_t)m * N + n] = acc[mi][ni][r] + bv;
      }
    }
  }
}

// Parity-compressed sliding-window attention. p = 2*qc+par: in compressed
// coords the dilated window is contiguous [qc-32, qc+32]. Block = 64 queries
// (one parity), stages exactly 128 K rows (bf16) + 128 V rows (fp32) in LDS.
// 4 threads per query, 16 dims each (d = u*32 + dq*8 + r).
__global__ __launch_bounds__(256) void patch_attn2(
    const float* __restrict__ qkv, float* __restrict__ attn) {
  constexpr int LDK = 80;  // ushorts per K row (64+16 pad: 2-way free)
  constexpr int LDV = 72;  // floats per V row (64+8 pad: 2-way free)
  __shared__ unsigned short Ks[128 * LDK];
  __shared__ float Vs[128 * LDV];

  const int t = threadIdx.x;
  const int qb = blockIdx.x;               // 0..15
  const int h = blockIdx.y;                // 0..7
  const int par = blockIdx.z & 1, b = blockIdx.z >> 1;
  const float* base = qkv + (size_t)b * S_LEN * QKV_LD;
  const int qc0 = qb * 64;

  // stage K (bf16) and V (fp32): rows jc in [qc0-32, qc0+96)
  {
    int rr = t >> 4;
    int cc = (t & 15) * 4;
#pragma unroll
    for (int pass = 0; pass < 8; pass++) {
      int r = pass * 16 + rr;
      int jc = qc0 - 32 + r;
      float4 kv = {0, 0, 0, 0}, vv = {0, 0, 0, 0};
      if (jc >= 0 && jc < P_LEN / 2) {
        const float* g =
            base + (size_t)(1 + 2 * jc + par) * QKV_LD + h * HD + cc;
        kv = *(const float4*)(g + 512);
        vv = *(const float4*)(g + 1024);
      }
      unsigned u0 = ((unsigned)f2bf(kv.y) << 16) | f2bf(kv.x);
      unsigned u1 = ((unsigned)f2bf(kv.w) << 16) | f2bf(kv.z);
      *(uint2*)&Ks[r * LDK + cc] = make_uint2(u0, u1);
      *(float4*)&Vs[r * LDV + cc] = vv;
    }
  }

  const int qi = t >> 2;  // query within block
  const int dq = t & 3;   // dim-quarter
  const int p = 2 * (qc0 + qi) + par;
  const float* qg = base + (size_t)(1 + p) * QKV_LD + h * HD;

  float q[16], o[16];
#pragma unroll
  for (int u = 0; u < 2; u++)
#pragma unroll
    for (int c8 = 0; c8 < 2; c8++) {
      float4 f = *(const float4*)(qg + u * 32 + dq * 8 + c8 * 4);
      int e = u * 8 + c8 * 4;
      q[e + 0] = f.x * SCALE;
      q[e + 1] = f.y * SCALE;
      q[e + 2] = f.z * SCALE;
      q[e + 3] = f.w * SCALE;
    }

  // cls key/value first (always valid): init m = s_cls, l = 1, o = v_cls
  const float* kc = base + 512 + h * HD;
  const float* vc = base + 1024 + h * HD;
  float pt = 0.f;
#pragma unroll
  for (int u = 0; u < 2; u++)
#pragma unroll
    for (int c8 = 0; c8 < 2; c8++) {
      float4 kf = *(const float4*)(kc + u * 32 + dq * 8 + c8 * 4);
      int e = u * 8 + c8 * 4;
      pt = fmaf(q[e + 0], kf.x, pt);
      pt = fmaf(q[e + 1], kf.y, pt);
      pt = fmaf(q[e + 2], kf.z, pt);
      pt = fmaf(q[e + 3], kf.w, pt);
    }
  pt += __shfl_xor(pt, 1, 4);
  pt += __shfl_xor(pt, 2, 4);
  float m = pt, l = 1.f;
#pragma unroll
  for (int u = 0; u < 2; u++)
#pragma unroll
    for (int c8 = 0; c8 < 2; c8++) {
      float4 vf = *(const float4*)(vc + u * 32 + dq * 8 + c8 * 4);
      int e = u * 8 + c8 * 4;
      o[e + 0] = vf.x;
      o[e + 1] = vf.y;
      o[e + 2] = vf.z;
      o[e + 3] = vf.w;
    }

  __syncthreads();

  for (int w = 0; w < 65; w++) {
    int jl = qi + w;  // staged row
    uint4 k0 = *(const uint4*)&Ks[jl * LDK + dq * 8];
    uint4 k1 = *(const uint4*)&Ks[jl * LDK + 32 + dq * 8];
    float s = 0.f;
    unsigned kw[8] = {k0.x, k0.y, k0.z, k0.w, k1.x, k1.y, k1.z, k1.w};
#pragma unroll
    for (int i = 0; i < 8; i++) {
      int e = (i >> 2) * 8 + (i & 3) * 2;
      s = fmaf(q[e + 0], __uint_as_float(kw[i] << 16), s);
      s = fmaf(q[e + 1], __uint_as_float(kw[i] & 0xffff0000u), s);
    }
    s += __shfl_xor(s, 1, 4);
    s += __shfl_xor(s, 2, 4);
    bool valid = (unsigned)(qc0 - 32 + jl) < (unsigned)(P_LEN / 2);
    if (valid) {
      float mn = fmaxf(m, s);
      float c0 = __expf(m - mn);
      float c1 = __expf(s - mn);
      l = l * c0 + c1;
      m = mn;
      const float* vr = &Vs[jl * LDV];
#pragma unroll
      for (int u = 0; u < 2; u++)
#pragma unroll
        for (int c8 = 0; c8 < 2; c8++) {
          float4 vf = *(const float4*)(vr + u * 32 + dq * 8 + c8 * 4);
          int e = u * 8 + c8 * 4;
          o[e + 0] = fmaf(c1, vf.x, o[e + 0] * c0);
          o[e + 1] = fmaf(c1, vf.y, o[e + 1] * c0);
          o[e + 2] = fmaf(c1, vf.z, o[e + 2] * c0);
          o[e + 3] = fmaf(c1, vf.w, o[e + 3] * c0);
        }
    }
  }

  float inv = 1.f / l;
  float* og = attn + ((size_t)b * S_LEN + 1 + p) * EMB + h * HD;
#pragma unroll
  for (int u = 0; u < 2; u++)
#pragma unroll
    for (int c8 = 0; c8 < 2; c8++) {
      int e = u * 8 + c8 * 4;
      float4 f = {o[e + 0] * inv, o[e + 1] * inv, o[e + 2] * inv,
                  o[e + 3] * inv};
      *(float4*)(og + u * 32 + dq * 8 + c8 * 4) = f;
    }
}

// CLS attention, split-K stage 1: grid (32 chunks, NH, B), block = 4 waves.
// Each block computes a partial online-softmax over its 64-key chunk and
// writes (m, l, o[64]) unnormalized partials to workspace.
__global__ __launch_bounds__(256) void cls_part_k(const float* __restrict__ qkv,
                                                  float* __restrict__ Pm,
                                                  float* __restrict__ Pl,
                                                  float* __restrict__ Po) {
  const int lane = threadIdx.x & 63;
  const int wv = threadIdx.x >> 6;  // 0..3
  const int ck = blockIdx.x;        // 0..31
  const int h = blockIdx.y;
  const int b = blockIdx.z;
  const float* base = qkv + (size_t)b * S_LEN * QKV_LD;
  float qd = base[h * HD + lane] * SCALE;

  int c0 = ck * 64;
  int cend = (ck == 31) ? S_LEN : c0 + 64;  // last chunk takes key 2048 too

  float m = -1e30f, l = 0.f, o = 0.f;
  for (int j = c0 + wv; j < cend; j += 4) {
    const float* krow = base + (size_t)j * QKV_LD + 512 + h * HD;
    float kv = krow[lane];
    float vv = krow[512 + lane];
    float s = wave_sum64(qd * kv);
    float mn = fmaxf(m, s);
    float e0 = __expf(m - mn);
    float e1 = __expf(s - mn);
    l = l * e0 + e1;
    o = o * e0 + e1 * vv;
    m = mn;
  }

  __shared__ float sm[4], sl[4], so[4][64];
  if (lane == 0) {
    sm[wv] = m;
    sl[wv] = l;
  }
  so[wv][lane] = o;
  __syncthreads();
  if (wv == 0) {
    float M = -1e30f;
#pragma unroll
    for (int i = 0; i < 4; i++) M = fmaxf(M, sm[i]);
    float L = 0.f, O = 0.f;
#pragma unroll
    for (int i = 0; i < 4; i++) {
      float c = __expf(sm[i] - M);
      L += sl[i] * c;
      O += so[i][lane] * c;
    }
    int idx = (b * NH + h) * 32 + ck;
    if (lane == 0) {
      Pm[idx] = M;
      Pl[idx] = L;
    }
    Po[(size_t)idx * 64 + lane] = O;
  }
}

// CLS split-K stage 2: combine 32 partials per (b,h). 16 blocks x 64 thr.
__global__ __launch_bounds__(64) void cls_comb_k(const float* __restrict__ Pm,
                                                 const float* __restrict__ Pl,
                                                 const float* __restrict__ Po,
                                                 float* __restrict__ attn) {
  const int lane = threadIdx.x;
  const int h = blockIdx.x % NH;
  const int b = blockIdx.x / NH;
  float m = -1e30f, l = 0.f, o = 0.f;
  for (int ck = 0; ck < 32; ck++) {
    int idx = (b * NH + h) * 32 + ck;
    float mc = Pm[idx];
    float lc = Pl[idx];
    float oc = Po[(size_t)idx * 64 + lane];
    float mn = fmaxf(m, mc);
    float e0 = __expf(m - mn);
    float e1 = __expf(mc - mn);
    l = l * e0 + lc * e1;
    o = o * e0 + oc * e1;
    m = mn;
  }
  attn[((size_t)b * S_LEN) * EMB + h * HD + lane] = o / l;
}

extern "C" void kernel_launch(void* const* d_in, const int* in_sizes, int n_in,
                              void* d_out, int out_size, void* d_ws,
                              size_t ws_size, hipStream_t stream) {
  const float* x = (const float*)d_in[0];
  const float* qkv_w = (const float*)d_in[1];
  const float* qkv_b = (const float*)d_in[2];
  const float* out_w = (const float*)d_in[3];
  const float* out_b = (const float*)d_in[4];
  float* out = (float*)d_out;

  float* qkv_buf = (float*)d_ws;                           // 2*2049*1536 f32
  float* attn_buf = qkv_buf + (size_t)2 * S_LEN * QKV_LD;  // 2*2049*512 f32
  float* cls_pm = attn_buf + (size_t)2 * S_LEN * EMB;      // 512 f32
  float* cls_pl = cls_pm + 512;                            // 512 f32
  float* cls_po = cls_pl + 512;                            // 32768 f32

  const int M = 2 * S_LEN;  // 4098

  dim3 gq((M + 127) / 128, QKV_LD / 128);  // 33 x 12
  gemm_split<128, 128><<<gq, 256, 0, stream>>>(x, qkv_w, qkv_b, qkv_buf, M,
                                               QKV_LD, EMB);

  cls_part_k<<<dim3(32, NH, 2), 256, 0, stream>>>(qkv_buf, cls_pm, cls_pl,
                                                  cls_po);
  cls_comb_k<<<2 * NH, 64, 0, stream>>>(cls_pm, cls_pl, cls_po, attn_buf);
  patch_attn2<<<dim3(16, NH, 4), 256, 0, stream>>>(qkv_buf, attn_buf);

  dim3 go((M + 127) / 128, EMB / 64);  // 33 x 8
  gemm_split<128, 64><<<go, 256, 0, stream>>>(attn_buf, out_w, out_b, out, M,
                                              EMB, EMB);
}

// Round 4
// 177.770 us; speedup vs baseline: 2.6132x; 1.0399x over previous
//
#include <hip/hip_runtime.h>
#include <math.h>

#define S_LEN 2049
#define P_LEN 2048
#define EMB 512
#define NH 8
#define HD 64
#define QKV_LD 1536
#define SCALE 0.125f

typedef __bf16 bf16x8 __attribute__((ext_vector_type(8)));
typedef float f32x4 __attribute__((ext_vector_type(4)));
typedef unsigned short u16x8 __attribute__((ext_vector_type(8)));

__device__ inline unsigned short f2bf(float f) {
  unsigned u = __float_as_uint(f);
  u += 0x7fff + ((u >> 16) & 1);  // RNE
  return (unsigned short)(u >> 16);
}
__device__ inline float bf2f(unsigned short h) {
  return __uint_as_float(((unsigned)h) << 16);
}

__device__ inline float wave_sum64(float v) {
#pragma unroll
  for (int off = 32; off > 0; off >>= 1) v += __shfl_xor(v, off, 64);
  return v;
}

// async global->LDS, 16B per lane; LDS dest = wave-uniform base + lane*16
__device__ inline void gld16(const unsigned* g, unsigned* l) {
  __builtin_amdgcn_global_load_lds(
      (const __attribute__((address_space(1))) unsigned*)g,
      (__attribute__((address_space(3))) unsigned*)l, 16, 0, 0);
}

// fp32 -> bf16 split converter. src is [*,512] f32 row-major; dst is
// [*,KO] bf16: hi at col+0 always; hi again at col+offHi2 (if >=0);
// lo at col+offLo (if >=0).
__global__ __launch_bounds__(256) void cvt_split(
    const float* __restrict__ src, unsigned short* __restrict__ dst, int total,
    int KO, int offHi2, int offLo) {
  int idx = (blockIdx.x * 256 + threadIdx.x) * 8;
  if (idx >= total) return;
  int row = idx >> 9;
  int col = idx & 511;
  float4 f0 = *(const float4*)(src + idx);
  float4 f1 = *(const float4*)(src + idx + 4);
  float ff[8] = {f0.x, f0.y, f0.z, f0.w, f1.x, f1.y, f1.z, f1.w};
  u16x8 vh, vl;
#pragma unroll
  for (int e = 0; e < 8; e++) {
    unsigned short hh = f2bf(ff[e]);
    vh[e] = hh;
    vl[e] = f2bf(ff[e] - bf2f(hh));
  }
  unsigned short* d = dst + (size_t)row * KO + col;
  *(u16x8*)d = vh;
  if (offHi2 >= 0) *(u16x8*)(d + offHi2) = vh;
  if (offLo >= 0) *(u16x8*)(d + offLo) = vl;
}

// Plain bf16 GEMM, m97 structure: C[M,N] = A[M,KP] @ B[N,KP]^T + bias.
// BM=128, BK=64, async global_load_lds staging with XOR-swizzled source
// columns so frag ds_read_b128 spreads over all 32 banks.
template <int BN>
__global__ __launch_bounds__(256) void gemm_bf16(
    const unsigned short* __restrict__ A, const unsigned short* __restrict__ B,
    const float* __restrict__ bias, float* __restrict__ C, int M, int N,
    int KP) {
  constexpr int BM = 128, BK = 64;
  __shared__ unsigned short As[BM * BK];
  __shared__ unsigned short Bs[BN * BK];
  const int t = threadIdx.x;
  const int lane = t & 63, wv = t >> 6;
  const int m0 = blockIdx.x * BM, n0 = blockIdx.y * BN;
  constexpr int WN = BN / 2;
  constexpr int RM = 4, RN = WN / 16;
  const int wm = wv & 1, wn = wv >> 1;
  const int lm = lane & 15, lq = lane >> 4;

  f32x4 acc[RM][RN];
#pragma unroll
  for (int i = 0; i < RM; i++)
#pragma unroll
    for (int j = 0; j < RN; j++) acc[i][j] = (f32x4){0.f, 0.f, 0.f, 0.f};

  // staging geometry: each wave-load covers 8 rows x 64 cols (1024 B).
  // lane i -> row lr = i/8, swizzled source chunk lc = (i%8) ^ lr.
  const int lr = lane >> 3;
  const int lc = (lane & 7) ^ lr;

  const unsigned* aptr[BM / 32];
#pragma unroll
  for (int p = 0; p < BM / 32; p++) {
    int ra = wv * 32 + p * 8 + lr;
    int gr = m0 + ra;
    gr = gr < M ? gr : M - 1;  // clamp source (epilogue store is guarded)
    aptr[p] = (const unsigned*)(A + (size_t)gr * KP + lc * 8);
  }
  const unsigned* bptr[BN / 32];
#pragma unroll
  for (int p = 0; p < BN / 32; p++) {
    int rb = wv * (BN / 4) + p * 8 + lr;
    bptr[p] = (const unsigned*)(B + (size_t)(n0 + rb) * KP + lc * 8);
  }

  for (int kt = 0; kt < KP; kt += BK) {
    __syncthreads();  // previous tile fully consumed
#pragma unroll
    for (int p = 0; p < BM / 32; p++)
      gld16(aptr[p] + (kt >> 1), (unsigned*)&As[(wv * 32 + p * 8) * BK]);
#pragma unroll
    for (int p = 0; p < BN / 32; p++)
      gld16(bptr[p] + (kt >> 1), (unsigned*)&Bs[(wv * (BN / 4) + p * 8) * BK]);
    __syncthreads();  // drain vmcnt + barrier

    bf16x8 fa[2][RM], fb[2][RN];
#pragma unroll
    for (int kk = 0; kk < 2; kk++) {
      int ch = ((kk * 4 + lq) ^ (lm & 7)) * 8;
#pragma unroll
      for (int mi = 0; mi < RM; mi++) {
        int ra = wm * 64 + mi * 16 + lm;
        fa[kk][mi] = *(const bf16x8*)&As[ra * BK + ch];
      }
#pragma unroll
      for (int ni = 0; ni < RN; ni++) {
        int rb = wn * WN + ni * 16 + lm;
        fb[kk][ni] = *(const bf16x8*)&Bs[rb * BK + ch];
      }
    }
#pragma unroll
    for (int kk = 0; kk < 2; kk++)
#pragma unroll
      for (int mi = 0; mi < RM; mi++)
#pragma unroll
        for (int ni = 0; ni < RN; ni++)
          acc[mi][ni] = __builtin_amdgcn_mfma_f32_16x16x32_bf16(
              fa[kk][mi], fb[kk][ni], acc[mi][ni], 0, 0, 0);
  }

  // C/D layout: col=lane&15 (=n), row=(lane>>4)*4+reg (=m)  [m89/m91]
#pragma unroll
  for (int ni = 0; ni < RN; ni++) {
    int n = n0 + wn * WN + ni * 16 + lm;
    float bv = bias[n];
#pragma unroll
    for (int mi = 0; mi < RM; mi++)
#pragma unroll
      for (int r = 0; r < 4; r++) {
        int m = m0 + wm * 64 + mi * 16 + lq * 4 + r;
        if (m < M) C[(size_t)m * N + n] = acc[mi][ni][r] + bv;
      }
  }
}

// Parity-compressed sliding-window attention (unchanged math); epilogue now
// writes bf16 hi/lo split directly into Aatt = [Oh|Ol|Oh] (out-proj A input).
__global__ __launch_bounds__(256) void patch_attn2(
    const float* __restrict__ qkv, unsigned short* __restrict__ Aatt) {
  constexpr int LDK = 80;
  constexpr int LDV = 72;
  __shared__ unsigned short Ks[128 * LDK];
  __shared__ float Vs[128 * LDV];

  const int t = threadIdx.x;
  const int qb = blockIdx.x;
  const int h = blockIdx.y;
  const int par = blockIdx.z & 1, b = blockIdx.z >> 1;
  const float* base = qkv + (size_t)b * S_LEN * QKV_LD;
  const int qc0 = qb * 64;

  {
    int rr = t >> 4;
    int cc = (t & 15) * 4;
#pragma unroll
    for (int pass = 0; pass < 8; pass++) {
      int r = pass * 16 + rr;
      int jc = qc0 - 32 + r;
      float4 kv = {0, 0, 0, 0}, vv = {0, 0, 0, 0};
      if (jc >= 0 && jc < P_LEN / 2) {
        const float* g =
            base + (size_t)(1 + 2 * jc + par) * QKV_LD + h * HD + cc;
        kv = *(const float4*)(g + 512);
        vv = *(const float4*)(g + 1024);
      }
      unsigned u0 = ((unsigned)f2bf(kv.y) << 16) | f2bf(kv.x);
      unsigned u1 = ((unsigned)f2bf(kv.w) << 16) | f2bf(kv.z);
      *(uint2*)&Ks[r * LDK + cc] = make_uint2(u0, u1);
      *(float4*)&Vs[r * LDV + cc] = vv;
    }
  }

  const int qi = t >> 2;
  const int dq = t & 3;
  const int p = 2 * (qc0 + qi) + par;
  const float* qg = base + (size_t)(1 + p) * QKV_LD + h * HD;

  float q[16], o[16];
#pragma unroll
  for (int u = 0; u < 2; u++)
#pragma unroll
    for (int c8 = 0; c8 < 2; c8++) {
      float4 f = *(const float4*)(qg + u * 32 + dq * 8 + c8 * 4);
      int e = u * 8 + c8 * 4;
      q[e + 0] = f.x * SCALE;
      q[e + 1] = f.y * SCALE;
      q[e + 2] = f.z * SCALE;
      q[e + 3] = f.w * SCALE;
    }

  const float* kc = base + 512 + h * HD;
  const float* vc = base + 1024 + h * HD;
  float pt = 0.f;
#pragma unroll
  for (int u = 0; u < 2; u++)
#pragma unroll
    for (int c8 = 0; c8 < 2; c8++) {
      float4 kf = *(const float4*)(kc + u * 32 + dq * 8 + c8 * 4);
      int e = u * 8 + c8 * 4;
      pt = fmaf(q[e + 0], kf.x, pt);
      pt = fmaf(q[e + 1], kf.y, pt);
      pt = fmaf(q[e + 2], kf.z, pt);
      pt = fmaf(q[e + 3], kf.w, pt);
    }
  pt += __shfl_xor(pt, 1, 4);
  pt += __shfl_xor(pt, 2, 4);
  float m = pt, l = 1.f;
#pragma unroll
  for (int u = 0; u < 2; u++)
#pragma unroll
    for (int c8 = 0; c8 < 2; c8++) {
      float4 vf = *(const float4*)(vc + u * 32 + dq * 8 + c8 * 4);
      int e = u * 8 + c8 * 4;
      o[e + 0] = vf.x;
      o[e + 1] = vf.y;
      o[e + 2] = vf.z;
      o[e + 3] = vf.w;
    }

  __syncthreads();

  for (int w = 0; w < 65; w++) {
    int jl = qi + w;
    uint4 k0 = *(const uint4*)&Ks[jl * LDK + dq * 8];
    uint4 k1 = *(const uint4*)&Ks[jl * LDK + 32 + dq * 8];
    float s = 0.f;
    unsigned kw[8] = {k0.x, k0.y, k0.z, k0.w, k1.x, k1.y, k1.z, k1.w};
#pragma unroll
    for (int i = 0; i < 8; i++) {
      int e = (i >> 2) * 8 + (i & 3) * 2;
      s = fmaf(q[e + 0], __uint_as_float(kw[i] << 16), s);
      s = fmaf(q[e + 1], __uint_as_float(kw[i] & 0xffff0000u), s);
    }
    s += __shfl_xor(s, 1, 4);
    s += __shfl_xor(s, 2, 4);
    bool valid = (unsigned)(qc0 - 32 + jl) < (unsigned)(P_LEN / 2);
    if (valid) {
      float mn = fmaxf(m, s);
      float c0 = __expf(m - mn);
      float c1 = __expf(s - mn);
      l = l * c0 + c1;
      m = mn;
      const float* vr = &Vs[jl * LDV];
#pragma unroll
      for (int u = 0; u < 2; u++)
#pragma unroll
        for (int c8 = 0; c8 < 2; c8++) {
          float4 vf = *(const float4*)(vr + u * 32 + dq * 8 + c8 * 4);
          int e = u * 8 + c8 * 4;
          o[e + 0] = fmaf(c1, vf.x, o[e + 0] * c0);
          o[e + 1] = fmaf(c1, vf.y, o[e + 1] * c0);
          o[e + 2] = fmaf(c1, vf.z, o[e + 2] * c0);
          o[e + 3] = fmaf(c1, vf.w, o[e + 3] * c0);
        }
    }
  }

  float inv = 1.f / l;
  unsigned short* ab = Aatt + ((size_t)b * S_LEN + 1 + p) * 1536;
#pragma unroll
  for (int u = 0; u < 2; u++) {
    u16x8 vh, vl;
#pragma unroll
    for (int j = 0; j < 8; j++) {
      float val = o[u * 8 + j] * inv;
      unsigned short hh = f2bf(val);
      vh[j] = hh;
      vl[j] = f2bf(val - bf2f(hh));
    }
    int colb = h * 64 + u * 32 + dq * 8;
    *(u16x8*)&ab[colb] = vh;
    *(u16x8*)&ab[512 + colb] = vl;
    *(u16x8*)&ab[1024 + colb] = vh;
  }
}

// CLS attention, split-K stage 1 (unchanged).
__global__ __launch_bounds__(256) void cls_part_k(const float* __restrict__ qkv,
                                                  float* __restrict__ Pm,
                                                  float* __restrict__ Pl,
                                                  float* __restrict__ Po) {
  const int lane = threadIdx.x & 63;
  const int wv = threadIdx.x >> 6;
  const int ck = blockIdx.x;
  const int h = blockIdx.y;
  const int b = blockIdx.z;
  const float* base = qkv + (size_t)b * S_LEN * QKV_LD;
  float qd = base[h * HD + lane] * SCALE;

  int c0 = ck * 64;
  int cend = (ck == 31) ? S_LEN : c0 + 64;

  float m = -1e30f, l = 0.f, o = 0.f;
  for (int j = c0 + wv; j < cend; j += 4) {
    const float* krow = base + (size_t)j * QKV_LD + 512 + h * HD;
    float kv = krow[lane];
    float vv = krow[512 + lane];
    float s = wave_sum64(qd * kv);
    float mn = fmaxf(m, s);
    float e0 = __expf(m - mn);
    float e1 = __expf(s - mn);
    l = l * e0 + e1;
    o = o * e0 + e1 * vv;
    m = mn;
  }

  __shared__ float sm[4], sl[4], so[4][64];
  if (lane == 0) {
    sm[wv] = m;
    sl[wv] = l;
  }
  so[wv][lane] = o;
  __syncthreads();
  if (wv == 0) {
    float M = -1e30f;
#pragma unroll
    for (int i = 0; i < 4; i++) M = fmaxf(M, sm[i]);
    float L = 0.f, O = 0.f;
#pragma unroll
    for (int i = 0; i < 4; i++) {
      float c = __expf(sm[i] - M);
      L += sl[i] * c;
      O += so[i][lane] * c;
    }
    int idx = (b * NH + h) * 32 + ck;
    if (lane == 0) {
      Pm[idx] = M;
      Pl[idx] = L;
    }
    Po[(size_t)idx * 64 + lane] = O;
  }
}

// CLS split-K stage 2: combine partials; write bf16 hi/lo into Aatt row 0.
__global__ __launch_bounds__(64) void cls_comb_k(const float* __restrict__ Pm,
                                                 const float* __restrict__ Pl,
                                                 const float* __restrict__ Po,
                                                 unsigned short* __restrict__ Aatt) {
  const int lane = threadIdx.x;
  const int h = blockIdx.x % NH;
  const int b = blockIdx.x / NH;
  float m = -1e30f, l = 0.f, o = 0.f;
  for (int ck = 0; ck < 32; ck++) {
    int idx = (b * NH + h) * 32 + ck;
    float mc = Pm[idx];
    float lc = Pl[idx];
    float oc = Po[(size_t)idx * 64 + lane];
    float mn = fmaxf(m, mc);
    float e0 = __expf(m - mn);
    float e1 = __expf(mc - mn);
    l = l * e0 + lc * e1;
    o = o * e0 + oc * e1;
    m = mn;
  }
  float val = o / l;
  unsigned short hh = f2bf(val);
  unsigned short ll = f2bf(val - bf2f(hh));
  unsigned short* ab = Aatt + (size_t)b * S_LEN * 1536;
  int col = h * HD + lane;
  ab[col] = hh;
  ab[512 + col] = ll;
  ab[1024 + col] = hh;
}

extern "C" void kernel_launch(void* const* d_in, const int* in_sizes, int n_in,
                              void* d_out, int out_size, void* d_ws,
                              size_t ws_size, hipStream_t stream) {
  const float* x = (const float*)d_in[0];
  const float* qkv_w = (const float*)d_in[1];
  const float* qkv_b = (const float*)d_in[2];
  const float* out_w = (const float*)d_in[3];
  const float* out_b = (const float*)d_in[4];
  float* out = (float*)d_out;

  const int M = 2 * S_LEN;  // 4098

  float* qkv_buf = (float*)d_ws;                  // 4098*1536 f32 (25.2 MB)
  float* cls_pm = qkv_buf + (size_t)M * QKV_LD;   // 512
  float* cls_pl = cls_pm + 512;                   // 512
  float* cls_po = cls_pl + 512;                   // 32768
  unsigned short* Xp = (unsigned short*)(cls_po + 32768);  // 4098*1024 bf16
  unsigned short* Wq = Xp + (size_t)M * 1024;              // 1536*1024 bf16
  unsigned short* Wo = Wq + (size_t)1536 * 1024;           // 512*1536 bf16
  unsigned short* Aatt = Wo + (size_t)512 * 1536;          // 4098*1536 bf16

  // converts: x -> [Xh|Xl]; qkv_w -> [Wh|Wh]; out_w -> [Wh|Wh|Wl]
  cvt_split<<<(M * EMB / 8 + 255) / 256, 256, 0, stream>>>(x, Xp, M * EMB,
                                                           1024, -1, 512);
  cvt_split<<<(QKV_LD * EMB / 8 + 255) / 256, 256, 0, stream>>>(
      qkv_w, Wq, QKV_LD * EMB, 1024, 512, -1);
  cvt_split<<<(EMB * EMB / 8 + 255) / 256, 256, 0, stream>>>(
      out_w, Wo, EMB * EMB, 1536, 512, 1024);

  // QKV projection: 2-term split-bf16 as plain GEMM over K'=1024
  dim3 gq((M + 127) / 128, QKV_LD / 128);  // 33 x 12
  gemm_bf16<128><<<gq, 256, 0, stream>>>(Xp, Wq, qkv_b, qkv_buf, M, QKV_LD,
                                         1024);

  cls_part_k<<<dim3(32, NH, 2), 256, 0, stream>>>(qkv_buf, cls_pm, cls_pl,
                                                  cls_po);
  cls_comb_k<<<2 * NH, 64, 0, stream>>>(cls_pm, cls_pl, cls_po, Aatt);
  patch_attn2<<<dim3(16, NH, 4), 256, 0, stream>>>(qkv_buf, Aatt);

  // Output projection: 3-term split-bf16 as plain GEMM over K'=1536
  dim3 go((M + 127) / 128, EMB / 64);  // 33 x 8
  gemm_bf16<64><<<go, 256, 0, stream>>>(Aatt, Wo, out_b, out, M, EMB, 1536);
}

// Round 6
// 165.940 us; speedup vs baseline: 2.7994x; 1.0713x over previous
//
#include <hip/hip_runtime.h>
#include <math.h>

#define S_LEN 2049
#define P_LEN 2048
#define EMB 512
#define NH 8
#define HD 64
#define QKV_LD 1536
#define SCALE 0.125f

typedef __bf16 bf16x8 __attribute__((ext_vector_type(8)));
typedef float f32x4 __attribute__((ext_vector_type(4)));
typedef unsigned short u16x8 __attribute__((ext_vector_type(8)));

__device__ inline unsigned short f2bf(float f) {
  unsigned u = __float_as_uint(f);
  u += 0x7fff + ((u >> 16) & 1);  // RNE
  return (unsigned short)(u >> 16);
}
__device__ inline float bf2f(unsigned short h) {
  return __uint_as_float(((unsigned)h) << 16);
}

__device__ inline float wave_sum64(float v) {
#pragma unroll
  for (int off = 32; off > 0; off >>= 1) v += __shfl_xor(v, off, 64);
  return v;
}

// async global->LDS, 16B per lane; LDS dest = wave-uniform base + lane*16
__device__ inline void gld16(const unsigned* g, unsigned* l) {
  __builtin_amdgcn_global_load_lds(
      (const __attribute__((address_space(1))) unsigned*)g,
      (__attribute__((address_space(3))) unsigned*)l, 16, 0, 0);
}

// fp32 -> bf16 split converter. src is [*,512] f32 row-major; dst is
// [*,KO] bf16: hi at col+0 always; hi again at col+offHi2 (if >=0);
// lo at col+offLo (if >=0).
__global__ __launch_bounds__(256) void cvt_split(
    const float* __restrict__ src, unsigned short* __restrict__ dst, int total,
    int KO, int offHi2, int offLo) {
  int idx = (blockIdx.x * 256 + threadIdx.x) * 8;
  if (idx >= total) return;
  int row = idx >> 9;
  int col = idx & 511;
  float4 f0 = *(const float4*)(src + idx);
  float4 f1 = *(const float4*)(src + idx + 4);
  float ff[8] = {f0.x, f0.y, f0.z, f0.w, f1.x, f1.y, f1.z, f1.w};
  u16x8 vh, vl;
#pragma unroll
  for (int e = 0; e < 8; e++) {
    unsigned short hh = f2bf(ff[e]);
    vh[e] = hh;
    vl[e] = f2bf(ff[e] - bf2f(hh));
  }
  unsigned short* d = dst + (size_t)row * KO + col;
  *(u16x8*)d = vh;
  if (offHi2 >= 0) *(u16x8*)(d + offHi2) = vh;
  if (offLo >= 0) *(u16x8*)(d + offLo) = vl;
}

// Plain bf16 GEMM, m97 structure, 2x2 wave tiling: C = A[M,KP] @ B[N,KP]^T + bias.
// BM=64 for occupancy at small grids (780/520 blocks vs 396/264).
template <int BM, int BN>
__global__ __launch_bounds__(256) void gemm_bf16(
    const unsigned short* __restrict__ A, const unsigned short* __restrict__ B,
    const float* __restrict__ bias, float* __restrict__ C, int M, int N,
    int KP) {
  constexpr int BK = 64;
  __shared__ unsigned short As[BM * BK];
  __shared__ unsigned short Bs[BN * BK];
  const int t = threadIdx.x;
  const int lane = t & 63, wv = t >> 6;
  const int m0 = blockIdx.x * BM, n0 = blockIdx.y * BN;
  constexpr int WM = BM / 2, WN = BN / 2;
  constexpr int RM = WM / 16, RN = WN / 16;
  const int wm = wv & 1, wn = wv >> 1;
  const int lm = lane & 15, lq = lane >> 4;

  f32x4 acc[RM][RN];
#pragma unroll
  for (int i = 0; i < RM; i++)
#pragma unroll
    for (int j = 0; j < RN; j++) acc[i][j] = (f32x4){0.f, 0.f, 0.f, 0.f};

  // staging: each wave-load covers 8 rows x 64 cols (1024 B); lane i ->
  // row lr=i/8, XOR-swizzled source chunk lc=(i%8)^lr (bank spread).
  const int lr = lane >> 3;
  const int lc = (lane & 7) ^ lr;

  const unsigned* aptr[BM / 32];
#pragma unroll
  for (int p = 0; p < BM / 32; p++) {
    int ra = wv * (BM / 4) + p * 8 + lr;
    int gr = m0 + ra;
    gr = gr < M ? gr : M - 1;  // clamp source (epilogue store is guarded)
    aptr[p] = (const unsigned*)(A + (size_t)gr * KP + lc * 8);
  }
  const unsigned* bptr[BN / 32];
#pragma unroll
  for (int p = 0; p < BN / 32; p++) {
    int rb = wv * (BN / 4) + p * 8 + lr;
    bptr[p] = (const unsigned*)(B + (size_t)(n0 + rb) * KP + lc * 8);
  }

  for (int kt = 0; kt < KP; kt += BK) {
    __syncthreads();
#pragma unroll
    for (int p = 0; p < BM / 32; p++)
      gld16(aptr[p] + (kt >> 1), (unsigned*)&As[(wv * (BM / 4) + p * 8) * BK]);
#pragma unroll
    for (int p = 0; p < BN / 32; p++)
      gld16(bptr[p] + (kt >> 1), (unsigned*)&Bs[(wv * (BN / 4) + p * 8) * BK]);
    __syncthreads();

    bf16x8 fa[2][RM], fb[2][RN];
#pragma unroll
    for (int kk = 0; kk < 2; kk++) {
      int ch = ((kk * 4 + lq) ^ (lm & 7)) * 8;
#pragma unroll
      for (int mi = 0; mi < RM; mi++) {
        int ra = wm * WM + mi * 16 + lm;
        fa[kk][mi] = *(const bf16x8*)&As[ra * BK + ch];
      }
#pragma unroll
      for (int ni = 0; ni < RN; ni++) {
        int rb = wn * WN + ni * 16 + lm;
        fb[kk][ni] = *(const bf16x8*)&Bs[rb * BK + ch];
      }
    }
#pragma unroll
    for (int kk = 0; kk < 2; kk++)
#pragma unroll
      for (int mi = 0; mi < RM; mi++)
#pragma unroll
        for (int ni = 0; ni < RN; ni++)
          acc[mi][ni] = __builtin_amdgcn_mfma_f32_16x16x32_bf16(
              fa[kk][mi], fb[kk][ni], acc[mi][ni], 0, 0, 0);
  }

  // C/D layout: col=lane&15 (=n), row=(lane>>4)*4+reg (=m)  [m89/m91]
#pragma unroll
  for (int ni = 0; ni < RN; ni++) {
    int n = n0 + wn * WN + ni * 16 + lm;
    float bv = bias[n];
#pragma unroll
    for (int mi = 0; mi < RM; mi++)
#pragma unroll
      for (int r = 0; r < 4; r++) {
        int m = m0 + wm * WM + mi * 16 + lq * 4 + r;
        if (m < M) C[(size_t)m * N + n] = acc[mi][ni][r] + bv;
      }
  }
}

// Parity-compressed sliding-window attention (round-4 proven version);
// epilogue writes bf16 hi/lo split directly into Aatt = [Oh|Ol|Oh].
__global__ __launch_bounds__(256) void patch_attn2(
    const float* __restrict__ qkv, unsigned short* __restrict__ Aatt) {
  constexpr int LDK = 80;
  constexpr int LDV = 72;
  __shared__ unsigned short Ks[128 * LDK];
  __shared__ float Vs[128 * LDV];

  const int t = threadIdx.x;
  const int qb = blockIdx.x;
  const int h = blockIdx.y;
  const int par = blockIdx.z & 1, b = blockIdx.z >> 1;
  const float* base = qkv + (size_t)b * S_LEN * QKV_LD;
  const int qc0 = qb * 64;

  {
    int rr = t >> 4;
    int cc = (t & 15) * 4;
#pragma unroll
    for (int pass = 0; pass < 8; pass++) {
      int r = pass * 16 + rr;
      int jc = qc0 - 32 + r;
      float4 kv = {0, 0, 0, 0}, vv = {0, 0, 0, 0};
      if (jc >= 0 && jc < P_LEN / 2) {
        const float* g =
            base + (size_t)(1 + 2 * jc + par) * QKV_LD + h * HD + cc;
        kv = *(const float4*)(g + 512);
        vv = *(const float4*)(g + 1024);
      }
      unsigned u0 = ((unsigned)f2bf(kv.y) << 16) | f2bf(kv.x);
      unsigned u1 = ((unsigned)f2bf(kv.w) << 16) | f2bf(kv.z);
      *(uint2*)&Ks[r * LDK + cc] = make_uint2(u0, u1);
      *(float4*)&Vs[r * LDV + cc] = vv;
    }
  }

  const int qi = t >> 2;
  const int dq = t & 3;
  const int p = 2 * (qc0 + qi) + par;
  const float* qg = base + (size_t)(1 + p) * QKV_LD + h * HD;

  float q[16], o[16];
#pragma unroll
  for (int u = 0; u < 2; u++)
#pragma unroll
    for (int c8 = 0; c8 < 2; c8++) {
      float4 f = *(const float4*)(qg + u * 32 + dq * 8 + c8 * 4);
      int e = u * 8 + c8 * 4;
      q[e + 0] = f.x * SCALE;
      q[e + 1] = f.y * SCALE;
      q[e + 2] = f.z * SCALE;
      q[e + 3] = f.w * SCALE;
    }

  const float* kc = base + 512 + h * HD;
  const float* vc = base + 1024 + h * HD;
  float pt = 0.f;
#pragma unroll
  for (int u = 0; u < 2; u++)
#pragma unroll
    for (int c8 = 0; c8 < 2; c8++) {
      float4 kf = *(const float4*)(kc + u * 32 + dq * 8 + c8 * 4);
      int e = u * 8 + c8 * 4;
      pt = fmaf(q[e + 0], kf.x, pt);
      pt = fmaf(q[e + 1], kf.y, pt);
      pt = fmaf(q[e + 2], kf.z, pt);
      pt = fmaf(q[e + 3], kf.w, pt);
    }
  pt += __shfl_xor(pt, 1, 4);
  pt += __shfl_xor(pt, 2, 4);
  float m = pt, l = 1.f;
#pragma unroll
  for (int u = 0; u < 2; u++)
#pragma unroll
    for (int c8 = 0; c8 < 2; c8++) {
      float4 vf = *(const float4*)(vc + u * 32 + dq * 8 + c8 * 4);
      int e = u * 8 + c8 * 4;
      o[e + 0] = vf.x;
      o[e + 1] = vf.y;
      o[e + 2] = vf.z;
      o[e + 3] = vf.w;
    }

  __syncthreads();

  for (int w = 0; w < 65; w++) {
    int jl = qi + w;
    uint4 k0 = *(const uint4*)&Ks[jl * LDK + dq * 8];
    uint4 k1 = *(const uint4*)&Ks[jl * LDK + 32 + dq * 8];
    float s = 0.f;
    unsigned kw[8] = {k0.x, k0.y, k0.z, k0.w, k1.x, k1.y, k1.z, k1.w};
#pragma unroll
    for (int i = 0; i < 8; i++) {
      int e = (i >> 2) * 8 + (i & 3) * 2;
      s = fmaf(q[e + 0], __uint_as_float(kw[i] << 16), s);
      s = fmaf(q[e + 1], __uint_as_float(kw[i] & 0xffff0000u), s);
    }
    s += __shfl_xor(s, 1, 4);
    s += __shfl_xor(s, 2, 4);
    bool valid = (unsigned)(qc0 - 32 + jl) < (unsigned)(P_LEN / 2);
    if (valid) {
      float mn = fmaxf(m, s);
      float c0 = __expf(m - mn);
      float c1 = __expf(s - mn);
      l = l * c0 + c1;
      m = mn;
      const float* vr = &Vs[jl * LDV];
#pragma unroll
      for (int u = 0; u < 2; u++)
#pragma unroll
        for (int c8 = 0; c8 < 2; c8++) {
          float4 vf = *(const float4*)(vr + u * 32 + dq * 8 + c8 * 4);
          int e = u * 8 + c8 * 4;
          o[e + 0] = fmaf(c1, vf.x, o[e + 0] * c0);
          o[e + 1] = fmaf(c1, vf.y, o[e + 1] * c0);
          o[e + 2] = fmaf(c1, vf.z, o[e + 2] * c0);
          o[e + 3] = fmaf(c1, vf.w, o[e + 3] * c0);
        }
    }
  }

  float inv = 1.f / l;
  unsigned short* ab = Aatt + ((size_t)b * S_LEN + 1 + p) * 1536;
#pragma unroll
  for (int u = 0; u < 2; u++) {
    u16x8 vh, vl;
#pragma unroll
    for (int j = 0; j < 8; j++) {
      float val = o[u * 8 + j] * inv;
      unsigned short hh = f2bf(val);
      vh[j] = hh;
      vl[j] = f2bf(val - bf2f(hh));
    }
    int colb = h * 64 + u * 32 + dq * 8;
    *(u16x8*)&ab[colb] = vh;
    *(u16x8*)&ab[512 + colb] = vl;
    *(u16x8*)&ab[1024 + colb] = vh;
  }
}

// CLS attention, split-K stage 1.
__global__ __launch_bounds__(256) void cls_part_k(const float* __restrict__ qkv,
                                                  float* __restrict__ Pm,
                                                  float* __restrict__ Pl,
                                                  float* __restrict__ Po) {
  const int lane = threadIdx.x & 63;
  const int wv = threadIdx.x >> 6;
  const int ck = blockIdx.x;
  const int h = blockIdx.y;
  const int b = blockIdx.z;
  const float* base = qkv + (size_t)b * S_LEN * QKV_LD;
  float qd = base[h * HD + lane] * SCALE;

  int c0 = ck * 64;
  int cend = (ck == 31) ? S_LEN : c0 + 64;

  float m = -1e30f, l = 0.f, o = 0.f;
  for (int j = c0 + wv; j < cend; j += 4) {
    const float* krow = base + (size_t)j * QKV_LD + 512 + h * HD;
    float kv = krow[lane];
    float vv = krow[512 + lane];
    float s = wave_sum64(qd * kv);
    float mn = fmaxf(m, s);
    float e0 = __expf(m - mn);
    float e1 = __expf(s - mn);
    l = l * e0 + e1;
    o = o * e0 + e1 * vv;
    m = mn;
  }

  __shared__ float sm[4], sl[4], so[4][64];
  if (lane == 0) {
    sm[wv] = m;
    sl[wv] = l;
  }
  so[wv][lane] = o;
  __syncthreads();
  if (wv == 0) {
    float M = -1e30f;
#pragma unroll
    for (int i = 0; i < 4; i++) M = fmaxf(M, sm[i]);
    float L = 0.f, O = 0.f;
#pragma unroll
    for (int i = 0; i < 4; i++) {
      float c = __expf(sm[i] - M);
      L += sl[i] * c;
      O += so[i][lane] * c;
    }
    int idx = (b * NH + h) * 32 + ck;
    if (lane == 0) {
      Pm[idx] = M;
      Pl[idx] = L;
    }
    Po[(size_t)idx * 64 + lane] = O;
  }
}

// CLS split-K stage 2: combine partials; write bf16 hi/lo into Aatt row 0.
__global__ __launch_bounds__(64) void cls_comb_k(
    const float* __restrict__ Pm, const float* __restrict__ Pl,
    const float* __restrict__ Po, unsigned short* __restrict__ Aatt) {
  const int lane = threadIdx.x;
  const int h = blockIdx.x % NH;
  const int b = blockIdx.x / NH;
  float m = -1e30f, l = 0.f, o = 0.f;
  for (int ck = 0; ck < 32; ck++) {
    int idx = (b * NH + h) * 32 + ck;
    float mc = Pm[idx];
    float lc = Pl[idx];
    float oc = Po[(size_t)idx * 64 + lane];
    float mn = fmaxf(m, mc);
    float e0 = __expf(m - mn);
    float e1 = __expf(mc - mn);
    l = l * e0 + lc * e1;
    o = o * e0 + oc * e1;
    m = mn;
  }
  float val = o / l;
  unsigned short hh = f2bf(val);
  unsigned short llo = f2bf(val - bf2f(hh));
  unsigned short* ab = Aatt + (size_t)b * S_LEN * 1536;
  int col = h * HD + lane;
  ab[col] = hh;
  ab[512 + col] = llo;
  ab[1024 + col] = hh;
}

extern "C" void kernel_launch(void* const* d_in, const int* in_sizes, int n_in,
                              void* d_out, int out_size, void* d_ws,
                              size_t ws_size, hipStream_t stream) {
  const float* x = (const float*)d_in[0];
  const float* qkv_w = (const float*)d_in[1];
  const float* qkv_b = (const float*)d_in[2];
  const float* out_w = (const float*)d_in[3];
  const float* out_b = (const float*)d_in[4];
  float* out = (float*)d_out;

  const int M = 2 * S_LEN;  // 4098

  float* qkv_buf = (float*)d_ws;                 // 4098*1536 f32 (25.2 MB)
  float* cls_pm = qkv_buf + (size_t)M * QKV_LD;  // 512
  float* cls_pl = cls_pm + 512;                  // 512
  float* cls_po = cls_pl + 512;                  // 32768
  unsigned short* Xp = (unsigned short*)(cls_po + 32768);  // 4098*1024 bf16
  unsigned short* Wq = Xp + (size_t)M * 1024;              // 1536*1024 bf16
  unsigned short* Wo = Wq + (size_t)1536 * 1024;           // 512*1536 bf16
  unsigned short* Aatt = Wo + (size_t)512 * 1536;          // 4098*1536 bf16

  // converts: x -> [Xh|Xl]; qkv_w -> [Wh|Wh]; out_w -> [Wh|Wh|Wl]
  cvt_split<<<(M * EMB / 8 + 255) / 256, 256, 0, stream>>>(x, Xp, M * EMB,
                                                           1024, -1, 512);
  cvt_split<<<(QKV_LD * EMB / 8 + 255) / 256, 256, 0, stream>>>(
      qkv_w, Wq, QKV_LD * EMB, 1024, 512, -1);
  cvt_split<<<(EMB * EMB / 8 + 255) / 256, 256, 0, stream>>>(
      out_w, Wo, EMB * EMB, 1536, 512, 1024);

  // QKV projection: 2-term split-bf16 as plain GEMM over K'=1024
  dim3 gq((M + 63) / 64, QKV_LD / 128);  // 65 x 12 = 780 blocks
  gemm_bf16<64, 128><<<gq, 256, 0, stream>>>(Xp, Wq, qkv_b, qkv_buf, M, QKV_LD,
                                             1024);

  cls_part_k<<<dim3(32, NH, 2), 256, 0, stream>>>(qkv_buf, cls_pm, cls_pl,
                                                  cls_po);
  cls_comb_k<<<2 * NH, 64, 0, stream>>>(cls_pm, cls_pl, cls_po, Aatt);
  patch_attn2<<<dim3(16, NH, 4), 256, 0, stream>>>(qkv_buf, Aatt);

  // Output projection: 3-term split-bf16 as plain GEMM over K'=1536
  dim3 go((M + 63) / 64, EMB / 64);  // 65 x 8 = 520 blocks
  gemm_bf16<64, 64><<<go, 256, 0, stream>>>(Aatt, Wo, out_b, out, M, EMB,
                                            1536);
}

// Round 7
// 151.813 us; speedup vs baseline: 3.0599x; 1.0931x over previous
//
#include <hip/hip_runtime.h>
#include <math.h>

#define S_LEN 2049
#define P_LEN 2048
#define EMB 512
#define NH 8
#define HD 64
#define QKV_LD 1536
#define SCALE 0.125f

typedef __bf16 bf16x8 __attribute__((ext_vector_type(8)));
typedef float f32x4 __attribute__((ext_vector_type(4)));
typedef unsigned short u16x8 __attribute__((ext_vector_type(8)));

__device__ inline unsigned short f2bf(float f) {
  unsigned u = __float_as_uint(f);
  u += 0x7fff + ((u >> 16) & 1);  // RNE
  return (unsigned short)(u >> 16);
}
__device__ inline float bf2f(unsigned short h) {
  return __uint_as_float(((unsigned)h) << 16);
}

__device__ inline float wave_sum64(float v) {
#pragma unroll
  for (int off = 32; off > 0; off >>= 1) v += __shfl_xor(v, off, 64);
  return v;
}

// async global->LDS, 16B per lane; LDS dest = wave-uniform base + lane*16
__device__ inline void gld16(const unsigned* g, unsigned* l) {
  __builtin_amdgcn_global_load_lds(
      (const __attribute__((address_space(1))) unsigned*)g,
      (__attribute__((address_space(3))) unsigned*)l, 16, 0, 0);
}

// fp32 -> bf16 split converter. src is [*,512] f32 row-major; dst is
// [*,KO] bf16: hi at col+0 always; hi again at col+offHi2 (if >=0);
// lo at col+offLo (if >=0).
__global__ __launch_bounds__(256) void cvt_split(
    const float* __restrict__ src, unsigned short* __restrict__ dst, int total,
    int KO, int offHi2, int offLo) {
  int idx = (blockIdx.x * 256 + threadIdx.x) * 8;
  if (idx >= total) return;
  int row = idx >> 9;
  int col = idx & 511;
  float4 f0 = *(const float4*)(src + idx);
  float4 f1 = *(const float4*)(src + idx + 4);
  float ff[8] = {f0.x, f0.y, f0.z, f0.w, f1.x, f1.y, f1.z, f1.w};
  u16x8 vh, vl;
#pragma unroll
  for (int e = 0; e < 8; e++) {
    unsigned short hh = f2bf(ff[e]);
    vh[e] = hh;
    vl[e] = f2bf(ff[e] - bf2f(hh));
  }
  unsigned short* d = dst + (size_t)row * KO + col;
  *(u16x8*)d = vh;
  if (offHi2 >= 0) *(u16x8*)(d + offHi2) = vh;
  if (offLo >= 0) *(u16x8*)(d + offLo) = vl;
}

// Plain bf16 GEMM, m97 structure, 2x2 wave tiling: C = A[M,KP] @ B[N,KP]^T + bias.
template <int BM, int BN>
__global__ __launch_bounds__(256) void gemm_bf16(
    const unsigned short* __restrict__ A, const unsigned short* __restrict__ B,
    const float* __restrict__ bias, float* __restrict__ C, int M, int N,
    int KP) {
  constexpr int BK = 64;
  __shared__ __align__(16) unsigned short As[BM * BK];
  __shared__ __align__(16) unsigned short Bs[BN * BK];
  const int t = threadIdx.x;
  const int lane = t & 63, wv = t >> 6;
  const int m0 = blockIdx.x * BM, n0 = blockIdx.y * BN;
  constexpr int WM = BM / 2, WN = BN / 2;
  constexpr int RM = WM / 16, RN = WN / 16;
  const int wm = wv & 1, wn = wv >> 1;
  const int lm = lane & 15, lq = lane >> 4;

  f32x4 acc[RM][RN];
#pragma unroll
  for (int i = 0; i < RM; i++)
#pragma unroll
    for (int j = 0; j < RN; j++) acc[i][j] = (f32x4){0.f, 0.f, 0.f, 0.f};

  const int lr = lane >> 3;
  const int lc = (lane & 7) ^ lr;  // XOR-swizzled source chunk (bank spread)

  const unsigned* aptr[BM / 32];
#pragma unroll
  for (int p = 0; p < BM / 32; p++) {
    int ra = wv * (BM / 4) + p * 8 + lr;
    int gr = m0 + ra;
    gr = gr < M ? gr : M - 1;  // clamp source (epilogue store is guarded)
    aptr[p] = (const unsigned*)(A + (size_t)gr * KP + lc * 8);
  }
  const unsigned* bptr[BN / 32];
#pragma unroll
  for (int p = 0; p < BN / 32; p++) {
    int rb = wv * (BN / 4) + p * 8 + lr;
    bptr[p] = (const unsigned*)(B + (size_t)(n0 + rb) * KP + lc * 8);
  }

  for (int kt = 0; kt < KP; kt += BK) {
    __syncthreads();
#pragma unroll
    for (int p = 0; p < BM / 32; p++)
      gld16(aptr[p] + (kt >> 1), (unsigned*)&As[(wv * (BM / 4) + p * 8) * BK]);
#pragma unroll
    for (int p = 0; p < BN / 32; p++)
      gld16(bptr[p] + (kt >> 1), (unsigned*)&Bs[(wv * (BN / 4) + p * 8) * BK]);
    __syncthreads();

    bf16x8 fa[2][RM], fb[2][RN];
#pragma unroll
    for (int kk = 0; kk < 2; kk++) {
      int ch = ((kk * 4 + lq) ^ (lm & 7)) * 8;
#pragma unroll
      for (int mi = 0; mi < RM; mi++) {
        int ra = wm * WM + mi * 16 + lm;
        fa[kk][mi] = *(const bf16x8*)&As[ra * BK + ch];
      }
#pragma unroll
      for (int ni = 0; ni < RN; ni++) {
        int rb = wn * WN + ni * 16 + lm;
        fb[kk][ni] = *(const bf16x8*)&Bs[rb * BK + ch];
      }
    }
#pragma unroll
    for (int kk = 0; kk < 2; kk++)
#pragma unroll
      for (int mi = 0; mi < RM; mi++)
#pragma unroll
        for (int ni = 0; ni < RN; ni++)
          acc[mi][ni] = __builtin_amdgcn_mfma_f32_16x16x32_bf16(
              fa[kk][mi], fb[kk][ni], acc[mi][ni], 0, 0, 0);
  }

  // C/D layout: col=lane&15 (=n), row=(lane>>4)*4+reg (=m)  [m89/m91]
#pragma unroll
  for (int ni = 0; ni < RN; ni++) {
    int n = n0 + wn * WN + ni * 16 + lm;
    float bv = bias[n];
#pragma unroll
    for (int mi = 0; mi < RM; mi++)
#pragma unroll
      for (int r = 0; r < 4; r++) {
        int m = m0 + wm * WM + mi * 16 + lq * 4 + r;
        if (m < M) C[(size_t)m * N + n] = acc[mi][ni][r] + bv;
      }
  }
}

// MFMA flash-window attention, HARDENED: all LDS zeroed before staging so no
// code path can observe residual LDS from prior kernels (round-5 post-timing
// divergence hypothesis: unwritten-LDS read; this kills the class).
__global__ __launch_bounds__(256) void patch_attn3(
    const float* __restrict__ qkv, unsigned short* __restrict__ Aatt) {
  constexpr int LDK = 72;   // ushort stride for Ks
  constexpr int LDT = 168;  // ushort stride for Vt/Ps
  __shared__ __align__(16) unsigned short Ks[144 * LDK];  // 20.25 KB
  __shared__ __align__(16) unsigned short Vt[64 * LDT];   // 21 KB
  __shared__ __align__(16) unsigned short Ps[64 * LDT];   // 21 KB

  const int t = threadIdx.x;
  const int lane = t & 63, wv = t >> 6;
  const int lm = lane & 15, lq = lane >> 4;
  const int qb = blockIdx.x;  // 0..15
  const int h = blockIdx.y;
  const int par = blockIdx.z & 1, b = blockIdx.z >> 1;
  const float* base = qkv + (size_t)b * S_LEN * QKV_LD;
  const int qc0 = qb * 64;

  // ---- defensive zero of ALL LDS ----
  {
    uint4 z = {0, 0, 0, 0};
    for (int i = t; i < 144 * LDK / 8; i += 256) ((uint4*)Ks)[i] = z;
    for (int i = t; i < 64 * LDT / 8; i += 256) ((uint4*)Vt)[i] = z;
    for (int i = t; i < 64 * LDT / 8; i += 256) ((uint4*)Ps)[i] = z;
  }
  __syncthreads();

  // ---- stage K: window rows 0..127, cls row 128 (129..143 stay zero) ----
  {
    int rr = t >> 4;
    int cc = (t & 15) * 4;
#pragma unroll
    for (int pass = 0; pass < 8; pass++) {
      int r = pass * 16 + rr;
      int jc = qc0 - 32 + r;
      float4 kv = {0, 0, 0, 0};
      if ((unsigned)jc < 1024u)
        kv = *(const float4*)(base + (size_t)(1 + 2 * jc + par) * QKV_LD +
                              512 + h * HD + cc);
      unsigned u0 = ((unsigned)f2bf(kv.y) << 16) | f2bf(kv.x);
      unsigned u1 = ((unsigned)f2bf(kv.w) << 16) | f2bf(kv.z);
      *(uint2*)&Ks[r * LDK + cc] = make_uint2(u0, u1);
    }
    if (rr == 0) {
      float4 kv = *(const float4*)(base + 512 + h * HD + cc);
      unsigned u0 = ((unsigned)f2bf(kv.y) << 16) | f2bf(kv.x);
      unsigned u1 = ((unsigned)f2bf(kv.w) << 16) | f2bf(kv.z);
      *(uint2*)&Ks[128 * LDK + cc] = make_uint2(u0, u1);
    }
  }
  // ---- stage V transposed: Vt[d][jl], jl 0..127; col 128 = cls V ----
#pragma unroll
  for (int pass = 0; pass < 4; pass++) {
    int task = pass * 256 + t;
    int jp = task >> 4;        // jl pair 0..63
    int d0 = (task & 15) * 4;  // d base
    int jc0 = qc0 - 32 + 2 * jp;
    float4 v0 = {0, 0, 0, 0}, v1 = {0, 0, 0, 0};
    if ((unsigned)jc0 < 1024u)
      v0 = *(const float4*)(base + (size_t)(1 + 2 * jc0 + par) * QKV_LD +
                            1024 + h * HD + d0);
    if ((unsigned)(jc0 + 1) < 1024u)
      v1 = *(const float4*)(base + (size_t)(1 + 2 * (jc0 + 1) + par) * QKV_LD +
                            1024 + h * HD + d0);
    float fv0[4] = {v0.x, v0.y, v0.z, v0.w};
    float fv1[4] = {v1.x, v1.y, v1.z, v1.w};
#pragma unroll
    for (int e = 0; e < 4; e++) {
      unsigned pk = ((unsigned)f2bf(fv1[e]) << 16) | f2bf(fv0[e]);
      *(unsigned*)&Vt[(d0 + e) * LDT + 2 * jp] = pk;
    }
  }
  if (t < 64) Vt[t * LDT + 128] = f2bf(base[1024 + h * HD + t]);

  // ---- Q fragments (A-frag: m=lane&15, k=quad*8+j), hi/lo split ----
  const int qi = wv * 16 + lm;
  const float* qg = base + (size_t)(1 + 2 * (qc0 + qi) + par) * QKV_LD + h * HD;
  bf16x8 qh[2], ql[2];
#pragma unroll
  for (int kk = 0; kk < 2; kk++) {
    float4 f0 = *(const float4*)(qg + kk * 32 + lq * 8);
    float4 f1 = *(const float4*)(qg + kk * 32 + lq * 8 + 4);
    float ff[8] = {f0.x, f0.y, f0.z, f0.w, f1.x, f1.y, f1.z, f1.w};
#pragma unroll
    for (int j = 0; j < 8; j++) {
      float v = ff[j] * SCALE;
      unsigned short hh = f2bf(v);
      qh[kk][j] = __builtin_bit_cast(__bf16, hh);
      unsigned short llo = f2bf(v - bf2f(hh));
      ql[kk][j] = __builtin_bit_cast(__bf16, llo);
    }
  }
  __syncthreads();

  // ---- S = Q·K^T : 9 N-tiles of 16 cols ----
  f32x4 s[9];
#pragma unroll
  for (int nt = 0; nt < 9; nt++) s[nt] = (f32x4){0.f, 0.f, 0.f, 0.f};
#pragma unroll
  for (int nt = 0; nt < 9; nt++) {
#pragma unroll
    for (int kk = 0; kk < 2; kk++) {
      bf16x8 kb = *(const bf16x8*)&Ks[(nt * 16 + lm) * LDK + kk * 32 + lq * 8];
      s[nt] = __builtin_amdgcn_mfma_f32_16x16x32_bf16(qh[kk], kb, s[nt], 0, 0, 0);
      s[nt] = __builtin_amdgcn_mfma_f32_16x16x32_bf16(ql[kk], kb, s[nt], 0, 0, 0);
    }
  }

  // ---- masked softmax per row (C/D: col=lane&15=jl%16, row=lq*4+r) ----
  float L[4];
#pragma unroll
  for (int r = 0; r < 4; r++) {
    int qrow = wv * 16 + lq * 4 + r;  // query index within 64-chunk
    float sv[9];
    float mx = -1e30f;
#pragma unroll
    for (int nt = 0; nt < 9; nt++) {
      int jl = nt * 16 + lm;
      bool valid =
          (jl == 128) ||
          (jl < 128 && jl >= qrow && jl <= qrow + 64 &&
           (unsigned)(qc0 - 32 + jl) < 1024u);
      sv[nt] = valid ? s[nt][r] : -1e30f;
      mx = fmaxf(mx, sv[nt]);
    }
#pragma unroll
    for (int off = 1; off < 16; off <<= 1)
      mx = fmaxf(mx, __shfl_xor(mx, off, 16));
    float l = 0.f;
#pragma unroll
    for (int nt = 0; nt < 9; nt++) {
      float e = __expf(sv[nt] - mx);
      l += e;
      Ps[qrow * LDT + nt * 16 + lm] = f2bf(e);
    }
#pragma unroll
    for (int off = 1; off < 16; off <<= 1) l += __shfl_xor(l, off, 16);
    L[r] = l;
  }
  __syncthreads();

  // ---- O = P·V : A=Ps rows (m=query), B=Vt rows (n=d), K=160 ----
  f32x4 oa[4];
#pragma unroll
  for (int nt = 0; nt < 4; nt++) oa[nt] = (f32x4){0.f, 0.f, 0.f, 0.f};
#pragma unroll
  for (int kc = 0; kc < 5; kc++) {
    bf16x8 pa = *(const bf16x8*)&Ps[(wv * 16 + lm) * LDT + kc * 32 + lq * 8];
#pragma unroll
    for (int nt = 0; nt < 4; nt++) {
      bf16x8 vb = *(const bf16x8*)&Vt[(nt * 16 + lm) * LDT + kc * 32 + lq * 8];
      oa[nt] = __builtin_amdgcn_mfma_f32_16x16x32_bf16(pa, vb, oa[nt], 0, 0, 0);
    }
  }

  // ---- epilogue: normalize, write bf16 hi/lo split [Oh|Ol|Oh] ----
#pragma unroll
  for (int r = 0; r < 4; r++) {
    float inv = 1.f / L[r];
    int qrow = wv * 16 + lq * 4 + r;
    int pp = 2 * (qc0 + qrow) + par;
    unsigned short* ab = Aatt + ((size_t)b * S_LEN + 1 + pp) * 1536 + h * 64;
#pragma unroll
    for (int nt = 0; nt < 4; nt++) {
      float val = oa[nt][r] * inv;
      int col = nt * 16 + lm;
      unsigned short hh = f2bf(val);
      unsigned short llo = f2bf(val - bf2f(hh));
      ab[col] = hh;
      ab[512 + col] = llo;
      ab[1024 + col] = hh;
    }
  }
}

// CLS attention, split-K stage 1.
__global__ __launch_bounds__(256) void cls_part_k(const float* __restrict__ qkv,
                                                  float* __restrict__ Pm,
                                                  float* __restrict__ Pl,
                                                  float* __restrict__ Po) {
  const int lane = threadIdx.x & 63;
  const int wv = threadIdx.x >> 6;
  const int ck = blockIdx.x;
  const int h = blockIdx.y;
  const int b = blockIdx.z;
  const float* base = qkv + (size_t)b * S_LEN * QKV_LD;
  float qd = base[h * HD + lane] * SCALE;

  int c0 = ck * 64;
  int cend = (ck == 31) ? S_LEN : c0 + 64;

  float m = -1e30f, l = 0.f, o = 0.f;
  for (int j = c0 + wv; j < cend; j += 4) {
    const float* krow = base + (size_t)j * QKV_LD + 512 + h * HD;
    float kv = krow[lane];
    float vv = krow[512 + lane];
    float s = wave_sum64(qd * kv);
    float mn = fmaxf(m, s);
    float e0 = __expf(m - mn);
    float e1 = __expf(s - mn);
    l = l * e0 + e1;
    o = o * e0 + e1 * vv;
    m = mn;
  }

  __shared__ float sm[4], sl[4], so[4][64];
  if (lane == 0) {
    sm[wv] = m;
    sl[wv] = l;
  }
  so[wv][lane] = o;
  __syncthreads();
  if (wv == 0) {
    float M = -1e30f;
#pragma unroll
    for (int i = 0; i < 4; i++) M = fmaxf(M, sm[i]);
    float L = 0.f, O = 0.f;
#pragma unroll
    for (int i = 0; i < 4; i++) {
      float c = __expf(sm[i] - M);
      L += sl[i] * c;
      O += so[i][lane] * c;
    }
    int idx = (b * NH + h) * 32 + ck;
    if (lane == 0) {
      Pm[idx] = M;
      Pl[idx] = L;
    }
    Po[(size_t)idx * 64 + lane] = O;
  }
}

// CLS split-K stage 2: combine partials; write bf16 hi/lo into Aatt row 0.
__global__ __launch_bounds__(64) void cls_comb_k(
    const float* __restrict__ Pm, const float* __restrict__ Pl,
    const float* __restrict__ Po, unsigned short* __restrict__ Aatt) {
  const int lane = threadIdx.x;
  const int h = blockIdx.x % NH;
  const int b = blockIdx.x / NH;
  float m = -1e30f, l = 0.f, o = 0.f;
  for (int ck = 0; ck < 32; ck++) {
    int idx = (b * NH + h) * 32 + ck;
    float mc = Pm[idx];
    float lc = Pl[idx];
    float oc = Po[(size_t)idx * 64 + lane];
    float mn = fmaxf(m, mc);
    float e0 = __expf(m - mn);
    float e1 = __expf(mc - mn);
    l = l * e0 + lc * e1;
    o = o * e0 + oc * e1;
    m = mn;
  }
  float val = o / l;
  unsigned short hh = f2bf(val);
  unsigned short llo = f2bf(val - bf2f(hh));
  unsigned short* ab = Aatt + (size_t)b * S_LEN * 1536;
  int col = h * HD + lane;
  ab[col] = hh;
  ab[512 + col] = llo;
  ab[1024 + col] = hh;
}

extern "C" void kernel_launch(void* const* d_in, const int* in_sizes, int n_in,
                              void* d_out, int out_size, void* d_ws,
                              size_t ws_size, hipStream_t stream) {
  const float* x = (const float*)d_in[0];
  const float* qkv_w = (const float*)d_in[1];
  const float* qkv_b = (const float*)d_in[2];
  const float* out_w = (const float*)d_in[3];
  const float* out_b = (const float*)d_in[4];
  float* out = (float*)d_out;

  const int M = 2 * S_LEN;  // 4098

  float* qkv_buf = (float*)d_ws;                 // 4098*1536 f32 (25.2 MB)
  float* cls_pm = qkv_buf + (size_t)M * QKV_LD;  // 512
  float* cls_pl = cls_pm + 512;                  // 512
  float* cls_po = cls_pl + 512;                  // 32768
  unsigned short* Xp = (unsigned short*)(cls_po + 32768);  // 4098*1024 bf16
  unsigned short* Wq = Xp + (size_t)M * 1024;              // 1536*1024 bf16
  unsigned short* Wo = Wq + (size_t)1536 * 1024;           // 512*1536 bf16
  unsigned short* Aatt = Wo + (size_t)512 * 1536;          // 4098*1536 bf16

  // converts: x -> [Xh|Xl]; qkv_w -> [Wh|Wh]; out_w -> [Wh|Wh|Wl]
  cvt_split<<<(M * EMB / 8 + 255) / 256, 256, 0, stream>>>(x, Xp, M * EMB,
                                                           1024, -1, 512);
  cvt_split<<<(QKV_LD * EMB / 8 + 255) / 256, 256, 0, stream>>>(
      qkv_w, Wq, QKV_LD * EMB, 1024, 512, -1);
  cvt_split<<<(EMB * EMB / 8 + 255) / 256, 256, 0, stream>>>(
      out_w, Wo, EMB * EMB, 1536, 512, 1024);

  // QKV projection: 2-term split-bf16 as plain GEMM over K'=1024
  dim3 gq((M + 63) / 64, QKV_LD / 128);  // 65 x 12 = 780 blocks
  gemm_bf16<64, 128><<<gq, 256, 0, stream>>>(Xp, Wq, qkv_b, qkv_buf, M, QKV_LD,
                                             1024);

  cls_part_k<<<dim3(32, NH, 2), 256, 0, stream>>>(qkv_buf, cls_pm, cls_pl,
                                                  cls_po);
  cls_comb_k<<<2 * NH, 64, 0, stream>>>(cls_pm, cls_pl, cls_po, Aatt);
  patch_attn3<<<dim3(16, NH, 4), 256, 0, stream>>>(qkv_buf, Aatt);

  // Output projection: 3-term split-bf16 as plain GEMM over K'=1536
  dim3 go((M + 63) / 64, EMB / 64);  // 65 x 8 = 520 blocks
  gemm_bf16<64, 64><<<go, 256, 0, stream>>>(Aatt, Wo, out_b, out, M, EMB,
                                            1536);
}

// Round 8
// 124.409 us; speedup vs baseline: 3.7340x; 1.2203x over previous
//
#include <hip/hip_runtime.h>
#include <math.h>

#define S_LEN 2049
#define P_LEN 2048
#define EMB 512
#define NH 8
#define HD 64
#define QKV_LD 1536
#define SCALE 0.125f

typedef _Float16 f16x8 __attribute__((ext_vector_type(8)));
typedef float f32x4 __attribute__((ext_vector_type(4)));
typedef unsigned short u16x8 __attribute__((ext_vector_type(8)));

__device__ inline unsigned short f2h(float f) {
  _Float16 h = (_Float16)f;  // RNE
  return __builtin_bit_cast(unsigned short, h);
}

__device__ inline float wave_sum64(float v) {
#pragma unroll
  for (int off = 32; off > 0; off >>= 1) v += __shfl_xor(v, off, 64);
  return v;
}

// async global->LDS, 16B per lane; LDS dest = wave-uniform base + lane*16
__device__ inline void gld16(const unsigned* g, unsigned* l) {
  __builtin_amdgcn_global_load_lds(
      (const __attribute__((address_space(1))) unsigned*)g,
      (__attribute__((address_space(3))) unsigned*)l, 16, 0, 0);
}

// fused fp32 -> fp16 converter for the three operands (x, qkv_w, out_w).
// All segment sizes are multiples of 8.
__global__ __launch_bounds__(256) void cvt3_f16(
    const float* __restrict__ s0, unsigned short* __restrict__ d0, int n0,
    const float* __restrict__ s1, unsigned short* __restrict__ d1, int n1,
    const float* __restrict__ s2, unsigned short* __restrict__ d2, int n2) {
  int idx = (blockIdx.x * 256 + threadIdx.x) * 8;
  const float* s;
  unsigned short* d;
  int off;
  if (idx < n0) {
    s = s0; d = d0; off = idx;
  } else if (idx < n0 + n1) {
    s = s1; d = d1; off = idx - n0;
  } else if (idx < n0 + n1 + n2) {
    s = s2; d = d2; off = idx - n0 - n1;
  } else {
    return;
  }
  float4 f0 = *(const float4*)(s + off);
  float4 f1 = *(const float4*)(s + off + 4);
  float ff[8] = {f0.x, f0.y, f0.z, f0.w, f1.x, f1.y, f1.z, f1.w};
  u16x8 vh;
#pragma unroll
  for (int e = 0; e < 8; e++) vh[e] = f2h(ff[e]);
  *(u16x8*)(d + off) = vh;
}

// Plain fp16 GEMM, m97 structure, 2x2 wave tiling: C = A[M,KP] @ B[N,KP]^T + bias.
template <int BM, int BN>
__global__ __launch_bounds__(256) void gemm_f16(
    const unsigned short* __restrict__ A, const unsigned short* __restrict__ B,
    const float* __restrict__ bias, float* __restrict__ C, int M, int N,
    int KP) {
  constexpr int BK = 64;
  __shared__ __align__(16) unsigned short As[BM * BK];
  __shared__ __align__(16) unsigned short Bs[BN * BK];
  const int t = threadIdx.x;
  const int lane = t & 63, wv = t >> 6;
  const int m0 = blockIdx.x * BM, n0 = blockIdx.y * BN;
  constexpr int WM = BM / 2, WN = BN / 2;
  constexpr int RM = WM / 16, RN = WN / 16;
  const int wm = wv & 1, wn = wv >> 1;
  const int lm = lane & 15, lq = lane >> 4;

  f32x4 acc[RM][RN];
#pragma unroll
  for (int i = 0; i < RM; i++)
#pragma unroll
    for (int j = 0; j < RN; j++) acc[i][j] = (f32x4){0.f, 0.f, 0.f, 0.f};

  const int lr = lane >> 3;
  const int lc = (lane & 7) ^ lr;  // XOR-swizzled source chunk (bank spread)

  const unsigned* aptr[BM / 32];
#pragma unroll
  for (int p = 0; p < BM / 32; p++) {
    int ra = wv * (BM / 4) + p * 8 + lr;
    int gr = m0 + ra;
    gr = gr < M ? gr : M - 1;  // clamp source (epilogue store is guarded)
    aptr[p] = (const unsigned*)(A + (size_t)gr * KP + lc * 8);
  }
  const unsigned* bptr[BN / 32];
#pragma unroll
  for (int p = 0; p < BN / 32; p++) {
    int rb = wv * (BN / 4) + p * 8 + lr;
    bptr[p] = (const unsigned*)(B + (size_t)(n0 + rb) * KP + lc * 8);
  }

  for (int kt = 0; kt < KP; kt += BK) {
    __syncthreads();
#pragma unroll
    for (int p = 0; p < BM / 32; p++)
      gld16(aptr[p] + (kt >> 1), (unsigned*)&As[(wv * (BM / 4) + p * 8) * BK]);
#pragma unroll
    for (int p = 0; p < BN / 32; p++)
      gld16(bptr[p] + (kt >> 1), (unsigned*)&Bs[(wv * (BN / 4) + p * 8) * BK]);
    __syncthreads();

    f16x8 fa[2][RM], fb[2][RN];
#pragma unroll
    for (int kk = 0; kk < 2; kk++) {
      int ch = ((kk * 4 + lq) ^ (lm & 7)) * 8;
#pragma unroll
      for (int mi = 0; mi < RM; mi++) {
        int ra = wm * WM + mi * 16 + lm;
        fa[kk][mi] = *(const f16x8*)&As[ra * BK + ch];
      }
#pragma unroll
      for (int ni = 0; ni < RN; ni++) {
        int rb = wn * WN + ni * 16 + lm;
        fb[kk][ni] = *(const f16x8*)&Bs[rb * BK + ch];
      }
    }
#pragma unroll
    for (int kk = 0; kk < 2; kk++)
#pragma unroll
      for (int mi = 0; mi < RM; mi++)
#pragma unroll
        for (int ni = 0; ni < RN; ni++)
          acc[mi][ni] = __builtin_amdgcn_mfma_f32_16x16x32_f16(
              fa[kk][mi], fb[kk][ni], acc[mi][ni], 0, 0, 0);
  }

  // C/D layout: col=lane&15 (=n), row=(lane>>4)*4+reg (=m)  [m89/m91]
#pragma unroll
  for (int ni = 0; ni < RN; ni++) {
    int n = n0 + wn * WN + ni * 16 + lm;
    float bv = bias[n];
#pragma unroll
    for (int mi = 0; mi < RM; mi++)
#pragma unroll
      for (int r = 0; r < 4; r++) {
        int m = m0 + wm * WM + mi * 16 + lq * 4 + r;
        if (m < M) C[(size_t)m * N + n] = acc[mi][ni][r] + bv;
      }
  }
}

// MFMA flash-window attention, fp16 operands. LDS fully zeroed before staging
// (round-5/7 lesson: residual-LDS reads caused post-timing divergence).
__global__ __launch_bounds__(256) void patch_attn3(
    const float* __restrict__ qkv, unsigned short* __restrict__ Aatt) {
  constexpr int LDK = 72;   // ushort stride for Ks
  constexpr int LDT = 168;  // ushort stride for Vt/Ps
  __shared__ __align__(16) unsigned short Ks[144 * LDK];  // 20.25 KB
  __shared__ __align__(16) unsigned short Vt[64 * LDT];   // 21 KB
  __shared__ __align__(16) unsigned short Ps[64 * LDT];   // 21 KB

  const int t = threadIdx.x;
  const int lane = t & 63, wv = t >> 6;
  const int lm = lane & 15, lq = lane >> 4;
  const int qb = blockIdx.x;  // 0..15
  const int h = blockIdx.y;
  const int par = blockIdx.z & 1, b = blockIdx.z >> 1;
  const float* base = qkv + (size_t)b * S_LEN * QKV_LD;
  const int qc0 = qb * 64;

  // ---- defensive zero of ALL LDS ----
  {
    uint4 z = {0, 0, 0, 0};
    for (int i = t; i < 144 * LDK / 8; i += 256) ((uint4*)Ks)[i] = z;
    for (int i = t; i < 64 * LDT / 8; i += 256) ((uint4*)Vt)[i] = z;
    for (int i = t; i < 64 * LDT / 8; i += 256) ((uint4*)Ps)[i] = z;
  }
  __syncthreads();

  // ---- stage K (fp16): window rows 0..127, cls row 128 ----
  {
    int rr = t >> 4;
    int cc = (t & 15) * 4;
#pragma unroll
    for (int pass = 0; pass < 8; pass++) {
      int r = pass * 16 + rr;
      int jc = qc0 - 32 + r;
      float4 kv = {0, 0, 0, 0};
      if ((unsigned)jc < 1024u)
        kv = *(const float4*)(base + (size_t)(1 + 2 * jc + par) * QKV_LD +
                              512 + h * HD + cc);
      unsigned u0 = ((unsigned)f2h(kv.y) << 16) | f2h(kv.x);
      unsigned u1 = ((unsigned)f2h(kv.w) << 16) | f2h(kv.z);
      *(uint2*)&Ks[r * LDK + cc] = make_uint2(u0, u1);
    }
    if (rr == 0) {
      float4 kv = *(const float4*)(base + 512 + h * HD + cc);
      unsigned u0 = ((unsigned)f2h(kv.y) << 16) | f2h(kv.x);
      unsigned u1 = ((unsigned)f2h(kv.w) << 16) | f2h(kv.z);
      *(uint2*)&Ks[128 * LDK + cc] = make_uint2(u0, u1);
    }
  }
  // ---- stage V transposed (fp16): Vt[d][jl], jl 0..127; col 128 = cls ----
#pragma unroll
  for (int pass = 0; pass < 4; pass++) {
    int task = pass * 256 + t;
    int jp = task >> 4;        // jl pair 0..63
    int d0 = (task & 15) * 4;  // d base
    int jc0 = qc0 - 32 + 2 * jp;
    float4 v0 = {0, 0, 0, 0}, v1 = {0, 0, 0, 0};
    if ((unsigned)jc0 < 1024u)
      v0 = *(const float4*)(base + (size_t)(1 + 2 * jc0 + par) * QKV_LD +
                            1024 + h * HD + d0);
    if ((unsigned)(jc0 + 1) < 1024u)
      v1 = *(const float4*)(base + (size_t)(1 + 2 * (jc0 + 1) + par) * QKV_LD +
                            1024 + h * HD + d0);
    float fv0[4] = {v0.x, v0.y, v0.z, v0.w};
    float fv1[4] = {v1.x, v1.y, v1.z, v1.w};
#pragma unroll
    for (int e = 0; e < 4; e++) {
      unsigned pk = ((unsigned)f2h(fv1[e]) << 16) | f2h(fv0[e]);
      *(unsigned*)&Vt[(d0 + e) * LDT + 2 * jp] = pk;
    }
  }
  if (t < 64) Vt[t * LDT + 128] = f2h(base[1024 + h * HD + t]);

  // ---- Q fragment (A-frag: m=lane&15, k=quad*8+j), single fp16 ----
  const int qi = wv * 16 + lm;
  const float* qg = base + (size_t)(1 + 2 * (qc0 + qi) + par) * QKV_LD + h * HD;
  f16x8 qf[2];
#pragma unroll
  for (int kk = 0; kk < 2; kk++) {
    float4 f0 = *(const float4*)(qg + kk * 32 + lq * 8);
    float4 f1 = *(const float4*)(qg + kk * 32 + lq * 8 + 4);
    float ff[8] = {f0.x, f0.y, f0.z, f0.w, f1.x, f1.y, f1.z, f1.w};
#pragma unroll
    for (int j = 0; j < 8; j++) qf[kk][j] = (_Float16)(ff[j] * SCALE);
  }
  __syncthreads();

  // ---- S = Q·K^T : 9 N-tiles of 16 cols ----
  f32x4 s[9];
#pragma unroll
  for (int nt = 0; nt < 9; nt++) s[nt] = (f32x4){0.f, 0.f, 0.f, 0.f};
#pragma unroll
  for (int nt = 0; nt < 9; nt++) {
#pragma unroll
    for (int kk = 0; kk < 2; kk++) {
      f16x8 kb = *(const f16x8*)&Ks[(nt * 16 + lm) * LDK + kk * 32 + lq * 8];
      s[nt] = __builtin_amdgcn_mfma_f32_16x16x32_f16(qf[kk], kb, s[nt], 0, 0, 0);
    }
  }

  // ---- masked softmax per row (C/D: col=lane&15=jl%16, row=lq*4+r) ----
  float L[4];
#pragma unroll
  for (int r = 0; r < 4; r++) {
    int qrow = wv * 16 + lq * 4 + r;  // query index within 64-chunk
    float sv[9];
    float mx = -1e30f;
#pragma unroll
    for (int nt = 0; nt < 9; nt++) {
      int jl = nt * 16 + lm;
      bool valid =
          (jl == 128) ||
          (jl < 128 && jl >= qrow && jl <= qrow + 64 &&
           (unsigned)(qc0 - 32 + jl) < 1024u);
      sv[nt] = valid ? s[nt][r] : -1e30f;
      mx = fmaxf(mx, sv[nt]);
    }
#pragma unroll
    for (int off = 1; off < 16; off <<= 1)
      mx = fmaxf(mx, __shfl_xor(mx, off, 16));
    float l = 0.f;
#pragma unroll
    for (int nt = 0; nt < 9; nt++) {
      float e = __expf(sv[nt] - mx);
      l += e;
      Ps[qrow * LDT + nt * 16 + lm] = f2h(e);
    }
#pragma unroll
    for (int off = 1; off < 16; off <<= 1) l += __shfl_xor(l, off, 16);
    L[r] = l;
  }
  __syncthreads();

  // ---- O = P·V : A=Ps rows (m=query), B=Vt rows (n=d), K=160 ----
  f32x4 oa[4];
#pragma unroll
  for (int nt = 0; nt < 4; nt++) oa[nt] = (f32x4){0.f, 0.f, 0.f, 0.f};
#pragma unroll
  for (int kc = 0; kc < 5; kc++) {
    f16x8 pa = *(const f16x8*)&Ps[(wv * 16 + lm) * LDT + kc * 32 + lq * 8];
#pragma unroll
    for (int nt = 0; nt < 4; nt++) {
      f16x8 vb = *(const f16x8*)&Vt[(nt * 16 + lm) * LDT + kc * 32 + lq * 8];
      oa[nt] = __builtin_amdgcn_mfma_f32_16x16x32_f16(pa, vb, oa[nt], 0, 0, 0);
    }
  }

  // ---- epilogue: normalize, write fp16 into Aatt[*, 512] ----
#pragma unroll
  for (int r = 0; r < 4; r++) {
    float inv = 1.f / L[r];
    int qrow = wv * 16 + lq * 4 + r;
    int pp = 2 * (qc0 + qrow) + par;
    unsigned short* ab = Aatt + ((size_t)b * S_LEN + 1 + pp) * 512 + h * 64;
#pragma unroll
    for (int nt = 0; nt < 4; nt++) ab[nt * 16 + lm] = f2h(oa[nt][r] * inv);
  }
}

// CLS attention, split-K stage 1.
__global__ __launch_bounds__(256) void cls_part_k(const float* __restrict__ qkv,
                                                  float* __restrict__ Pm,
                                                  float* __restrict__ Pl,
                                                  float* __restrict__ Po) {
  const int lane = threadIdx.x & 63;
  const int wv = threadIdx.x >> 6;
  const int ck = blockIdx.x;
  const int h = blockIdx.y;
  const int b = blockIdx.z;
  const float* base = qkv + (size_t)b * S_LEN * QKV_LD;
  float qd = base[h * HD + lane] * SCALE;

  int c0 = ck * 64;
  int cend = (ck == 31) ? S_LEN : c0 + 64;

  float m = -1e30f, l = 0.f, o = 0.f;
  for (int j = c0 + wv; j < cend; j += 4) {
    const float* krow = base + (size_t)j * QKV_LD + 512 + h * HD;
    float kv = krow[lane];
    float vv = krow[512 + lane];
    float s = wave_sum64(qd * kv);
    float mn = fmaxf(m, s);
    float e0 = __expf(m - mn);
    float e1 = __expf(s - mn);
    l = l * e0 + e1;
    o = o * e0 + e1 * vv;
    m = mn;
  }

  __shared__ float sm[4], sl[4], so[4][64];
  if (lane == 0) {
    sm[wv] = m;
    sl[wv] = l;
  }
  so[wv][lane] = o;
  __syncthreads();
  if (wv == 0) {
    float M = -1e30f;
#pragma unroll
    for (int i = 0; i < 4; i++) M = fmaxf(M, sm[i]);
    float L = 0.f, O = 0.f;
#pragma unroll
    for (int i = 0; i < 4; i++) {
      float c = __expf(sm[i] - M);
      L += sl[i] * c;
      O += so[i][lane] * c;
    }
    int idx = (b * NH + h) * 32 + ck;
    if (lane == 0) {
      Pm[idx] = M;
      Pl[idx] = L;
    }
    Po[(size_t)idx * 64 + lane] = O;
  }
}

// CLS split-K stage 2: combine partials; write fp16 into Aatt row 0.
__global__ __launch_bounds__(64) void cls_comb_k(
    const float* __restrict__ Pm, const float* __restrict__ Pl,
    const float* __restrict__ Po, unsigned short* __restrict__ Aatt) {
  const int lane = threadIdx.x;
  const int h = blockIdx.x % NH;
  const int b = blockIdx.x / NH;
  float m = -1e30f, l = 0.f, o = 0.f;
  for (int ck = 0; ck < 32; ck++) {
    int idx = (b * NH + h) * 32 + ck;
    float mc = Pm[idx];
    float lc = Pl[idx];
    float oc = Po[(size_t)idx * 64 + lane];
    float mn = fmaxf(m, mc);
    float e0 = __expf(m - mn);
    float e1 = __expf(mc - mn);
    l = l * e0 + lc * e1;
    o = o * e0 + oc * e1;
    m = mn;
  }
  Aatt[(size_t)b * S_LEN * 512 + h * HD + lane] = f2h(o / l);
}

extern "C" void kernel_launch(void* const* d_in, const int* in_sizes, int n_in,
                              void* d_out, int out_size, void* d_ws,
                              size_t ws_size, hipStream_t stream) {
  const float* x = (const float*)d_in[0];
  const float* qkv_w = (const float*)d_in[1];
  const float* qkv_b = (const float*)d_in[2];
  const float* out_w = (const float*)d_in[3];
  const float* out_b = (const float*)d_in[4];
  float* out = (float*)d_out;

  const int M = 2 * S_LEN;  // 4098

  float* qkv_buf = (float*)d_ws;                 // 4098*1536 f32 (25.2 MB)
  float* cls_pm = qkv_buf + (size_t)M * QKV_LD;  // 512
  float* cls_pl = cls_pm + 512;                  // 512
  float* cls_po = cls_pl + 512;                  // 32768
  unsigned short* Xp = (unsigned short*)(cls_po + 32768);  // 4098*512 fp16
  unsigned short* Wq = Xp + (size_t)M * 512;               // 1536*512 fp16
  unsigned short* Wo = Wq + (size_t)1536 * 512;            // 512*512 fp16
  unsigned short* Aatt = Wo + (size_t)512 * 512;           // 4098*512 fp16

  const int n0 = M * EMB;        // 2098176
  const int n1 = QKV_LD * EMB;   // 786432
  const int n2 = EMB * EMB;      // 262144
  int cvt_blocks = ((n0 + n1 + n2) / 8 + 255) / 256;
  cvt3_f16<<<cvt_blocks, 256, 0, stream>>>(x, Xp, n0, qkv_w, Wq, n1, out_w, Wo,
                                           n2);

  // QKV projection: single-term fp16 GEMM, K=512
  dim3 gq((M + 63) / 64, QKV_LD / 128);  // 65 x 12 = 780 blocks
  gemm_f16<64, 128><<<gq, 256, 0, stream>>>(Xp, Wq, qkv_b, qkv_buf, M, QKV_LD,
                                            512);

  cls_part_k<<<dim3(32, NH, 2), 256, 0, stream>>>(qkv_buf, cls_pm, cls_pl,
                                                  cls_po);
  cls_comb_k<<<2 * NH, 64, 0, stream>>>(cls_pm, cls_pl, cls_po, Aatt);
  patch_attn3<<<dim3(16, NH, 4), 256, 0, stream>>>(qkv_buf, Aatt);

  // Output projection: single-term fp16 GEMM, K=512
  dim3 go((M + 63) / 64, EMB / 64);  // 65 x 8 = 520 blocks
  gemm_f16<64, 64><<<go, 256, 0, stream>>>(Aatt, Wo, out_b, out, M, EMB, 512);
}

// Round 9
// 122.145 us; speedup vs baseline: 3.8032x; 1.0185x over previous
//
#include <hip/hip_runtime.h>
#include <math.h>

#define S_LEN 2049
#define P_LEN 2048
#define EMB 512
#define NH 8
#define HD 64
#define SCALE 0.125f

typedef _Float16 f16x8 __attribute__((ext_vector_type(8)));
typedef float f32x4 __attribute__((ext_vector_type(4)));
typedef unsigned short u16x8 __attribute__((ext_vector_type(8)));

__device__ inline unsigned short f2h(float f) {
  _Float16 h = (_Float16)f;  // RNE
  return __builtin_bit_cast(unsigned short, h);
}
__device__ inline float h2f(unsigned short u) {
  return (float)__builtin_bit_cast(_Float16, u);
}

__device__ inline float wave_sum64(float v) {
#pragma unroll
  for (int off = 32; off > 0; off >>= 1) v += __shfl_xor(v, off, 64);
  return v;
}

// async global->LDS, 16B per lane; LDS dest = wave-uniform base + lane*16
__device__ inline void gld16(const unsigned* g, unsigned* l) {
  __builtin_amdgcn_global_load_lds(
      (const __attribute__((address_space(1))) unsigned*)g,
      (__attribute__((address_space(3))) unsigned*)l, 16, 0, 0);
}

// fused fp32 -> fp16 converter for the three operands (x, qkv_w, out_w).
__global__ __launch_bounds__(256) void cvt3_f16(
    const float* __restrict__ s0, unsigned short* __restrict__ d0, int n0,
    const float* __restrict__ s1, unsigned short* __restrict__ d1, int n1,
    const float* __restrict__ s2, unsigned short* __restrict__ d2, int n2) {
  int idx = (blockIdx.x * 256 + threadIdx.x) * 8;
  const float* s;
  unsigned short* d;
  int off;
  if (idx < n0) {
    s = s0; d = d0; off = idx;
  } else if (idx < n0 + n1) {
    s = s1; d = d1; off = idx - n0;
  } else if (idx < n0 + n1 + n2) {
    s = s2; d = d2; off = idx - n0 - n1;
  } else {
    return;
  }
  float4 f0 = *(const float4*)(s + off);
  float4 f1 = *(const float4*)(s + off + 4);
  float ff[8] = {f0.x, f0.y, f0.z, f0.w, f1.x, f1.y, f1.z, f1.w};
  u16x8 vh;
#pragma unroll
  for (int e = 0; e < 8; e++) vh[e] = f2h(ff[e]);
  *(u16x8*)(d + off) = vh;
}

// Plain fp16 GEMM, m97 structure, 2x2 wave tiling: C = A[M,KP] @ B[N,KP]^T + bias.
// F16OUT: store C as fp16 (bias still fp32-added) instead of fp32.
template <int BM, int BN, bool F16OUT>
__global__ __launch_bounds__(256) void gemm_f16(
    const unsigned short* __restrict__ A, const unsigned short* __restrict__ B,
    const float* __restrict__ bias, void* __restrict__ Cv, int M, int N,
    int KP) {
  constexpr int BK = 64;
  __shared__ __align__(16) unsigned short As[BM * BK];
  __shared__ __align__(16) unsigned short Bs[BN * BK];
  const int t = threadIdx.x;
  const int lane = t & 63, wv = t >> 6;
  const int m0 = blockIdx.x * BM, n0 = blockIdx.y * BN;
  constexpr int WM = BM / 2, WN = BN / 2;
  constexpr int RM = WM / 16, RN = WN / 16;
  const int wm = wv & 1, wn = wv >> 1;
  const int lm = lane & 15, lq = lane >> 4;

  f32x4 acc[RM][RN];
#pragma unroll
  for (int i = 0; i < RM; i++)
#pragma unroll
    for (int j = 0; j < RN; j++) acc[i][j] = (f32x4){0.f, 0.f, 0.f, 0.f};

  const int lr = lane >> 3;
  const int lc = (lane & 7) ^ lr;  // XOR-swizzled source chunk (bank spread)

  const unsigned* aptr[BM / 32];
#pragma unroll
  for (int p = 0; p < BM / 32; p++) {
    int ra = wv * (BM / 4) + p * 8 + lr;
    int gr = m0 + ra;
    gr = gr < M ? gr : M - 1;  // clamp source (epilogue store is guarded)
    aptr[p] = (const unsigned*)(A + (size_t)gr * KP + lc * 8);
  }
  const unsigned* bptr[BN / 32];
#pragma unroll
  for (int p = 0; p < BN / 32; p++) {
    int rb = wv * (BN / 4) + p * 8 + lr;
    bptr[p] = (const unsigned*)(B + (size_t)(n0 + rb) * KP + lc * 8);
  }

  for (int kt = 0; kt < KP; kt += BK) {
    __syncthreads();
#pragma unroll
    for (int p = 0; p < BM / 32; p++)
      gld16(aptr[p] + (kt >> 1), (unsigned*)&As[(wv * (BM / 4) + p * 8) * BK]);
#pragma unroll
    for (int p = 0; p < BN / 32; p++)
      gld16(bptr[p] + (kt >> 1), (unsigned*)&Bs[(wv * (BN / 4) + p * 8) * BK]);
    __syncthreads();

    f16x8 fa[2][RM], fb[2][RN];
#pragma unroll
    for (int kk = 0; kk < 2; kk++) {
      int ch = ((kk * 4 + lq) ^ (lm & 7)) * 8;
#pragma unroll
      for (int mi = 0; mi < RM; mi++) {
        int ra = wm * WM + mi * 16 + lm;
        fa[kk][mi] = *(const f16x8*)&As[ra * BK + ch];
      }
#pragma unroll
      for (int ni = 0; ni < RN; ni++) {
        int rb = wn * WN + ni * 16 + lm;
        fb[kk][ni] = *(const f16x8*)&Bs[rb * BK + ch];
      }
    }
#pragma unroll
    for (int kk = 0; kk < 2; kk++)
#pragma unroll
      for (int mi = 0; mi < RM; mi++)
#pragma unroll
        for (int ni = 0; ni < RN; ni++)
          acc[mi][ni] = __builtin_amdgcn_mfma_f32_16x16x32_f16(
              fa[kk][mi], fb[kk][ni], acc[mi][ni], 0, 0, 0);
  }

  // C/D layout: col=lane&15 (=n), row=(lane>>4)*4+reg (=m)  [m89/m91]
#pragma unroll
  for (int ni = 0; ni < RN; ni++) {
    int n = n0 + wn * WN + ni * 16 + lm;
    float bv = bias[n];
#pragma unroll
    for (int mi = 0; mi < RM; mi++)
#pragma unroll
      for (int r = 0; r < 4; r++) {
        int m = m0 + wm * WM + mi * 16 + lq * 4 + r;
        if (m < M) {
          float val = acc[mi][ni][r] + bv;
          if constexpr (F16OUT)
            ((unsigned short*)Cv)[(size_t)m * N + n] = f2h(val);
          else
            ((float*)Cv)[(size_t)m * N + n] = val;
        }
      }
  }
}

// MFMA flash-window attention over fp16 qkv. Staging is now pure copy (no
// conversion); SCALE applied post-MFMA on fp32 logits. LDS fully zeroed first
// (round-5/7 lesson: residual-LDS reads caused post-timing divergence).
__global__ __launch_bounds__(256) void patch_attn3(
    const unsigned short* __restrict__ qkv16,
    unsigned short* __restrict__ Aatt) {
  constexpr int LDK = 72;   // ushort stride for Ks (144 B rows, 16B-aligned)
  constexpr int LDT = 168;  // ushort stride for Vt/Ps
  __shared__ __align__(16) unsigned short Ks[144 * LDK];  // 20.25 KB
  __shared__ __align__(16) unsigned short Vt[64 * LDT];   // 21 KB
  __shared__ __align__(16) unsigned short Ps[64 * LDT];   // 21 KB

  const int t = threadIdx.x;
  const int lane = t & 63, wv = t >> 6;
  const int lm = lane & 15, lq = lane >> 4;
  const int qb = blockIdx.x;  // 0..15
  const int h = blockIdx.y;
  const int par = blockIdx.z & 1, b = blockIdx.z >> 1;
  const unsigned short* base = qkv16 + (size_t)b * S_LEN * 1536;
  const int qc0 = qb * 64;

  // ---- defensive zero of ALL LDS ----
  {
    uint4 z = {0, 0, 0, 0};
    for (int i = t; i < 144 * LDK / 8; i += 256) ((uint4*)Ks)[i] = z;
    for (int i = t; i < 64 * LDT / 8; i += 256) ((uint4*)Vt)[i] = z;
    for (int i = t; i < 64 * LDT / 8; i += 256) ((uint4*)Ps)[i] = z;
  }
  __syncthreads();

  // ---- stage K (direct fp16 copy): window rows 0..127, cls row 128 ----
  {
    int rr = t >> 4;
    int cc = (t & 15) * 4;  // 4 halves (8 B) per thread
#pragma unroll
    for (int pass = 0; pass < 8; pass++) {
      int r = pass * 16 + rr;
      int jc = qc0 - 32 + r;
      uint2 kv = {0, 0};
      if ((unsigned)jc < 1024u)
        kv = *(const uint2*)(base + (size_t)(1 + 2 * jc + par) * 1536 + 512 +
                             h * 64 + cc);
      *(uint2*)&Ks[r * LDK + cc] = kv;
    }
    if (rr == 0)
      *(uint2*)&Ks[128 * LDK + cc] =
          *(const uint2*)(base + 512 + h * 64 + cc);
  }
  // ---- stage V transposed: Vt[d][jl] via half-pair repack ----
#pragma unroll
  for (int pass = 0; pass < 4; pass++) {
    int task = pass * 256 + t;
    int jp = task >> 4;        // jl pair 0..63
    int d0 = (task & 15) * 4;  // dim base
    int jc0 = qc0 - 32 + 2 * jp;
    uint2 a = {0, 0}, c = {0, 0};
    if ((unsigned)jc0 < 1024u)
      a = *(const uint2*)(base + (size_t)(1 + 2 * jc0 + par) * 1536 + 1024 +
                          h * 64 + d0);
    if ((unsigned)(jc0 + 1) < 1024u)
      c = *(const uint2*)(base + (size_t)(1 + 2 * (jc0 + 1) + par) * 1536 +
                          1024 + h * 64 + d0);
    *(unsigned*)&Vt[(d0 + 0) * LDT + 2 * jp] = (a.x & 0xffffu) | (c.x << 16);
    *(unsigned*)&Vt[(d0 + 1) * LDT + 2 * jp] = (a.x >> 16) | (c.x & 0xffff0000u);
    *(unsigned*)&Vt[(d0 + 2) * LDT + 2 * jp] = (a.y & 0xffffu) | (c.y << 16);
    *(unsigned*)&Vt[(d0 + 3) * LDT + 2 * jp] = (a.y >> 16) | (c.y & 0xffff0000u);
  }
  if (t < 64) Vt[t * LDT + 128] = base[1024 + h * 64 + t];  // cls V col

  // ---- Q fragment: direct f16x8 loads (A-frag: m=lane&15, k=quad*8+j) ----
  const int qi = wv * 16 + lm;
  const unsigned short* qg =
      base + (size_t)(1 + 2 * (qc0 + qi) + par) * 1536 + h * 64;
  f16x8 qf[2];
  qf[0] = *(const f16x8*)&qg[lq * 8];
  qf[1] = *(const f16x8*)&qg[32 + lq * 8];
  __syncthreads();

  // ---- S = Q·K^T : 9 N-tiles of 16 cols ----
  f32x4 s[9];
#pragma unroll
  for (int nt = 0; nt < 9; nt++) s[nt] = (f32x4){0.f, 0.f, 0.f, 0.f};
#pragma unroll
  for (int nt = 0; nt < 9; nt++) {
#pragma unroll
    for (int kk = 0; kk < 2; kk++) {
      f16x8 kb = *(const f16x8*)&Ks[(nt * 16 + lm) * LDK + kk * 32 + lq * 8];
      s[nt] =
          __builtin_amdgcn_mfma_f32_16x16x32_f16(qf[kk], kb, s[nt], 0, 0, 0);
    }
  }

  // ---- masked softmax per row; SCALE applied here (post-MFMA, fp32) ----
  float L[4];
#pragma unroll
  for (int r = 0; r < 4; r++) {
    int qrow = wv * 16 + lq * 4 + r;  // query index within 64-chunk
    float sv[9];
    float mx = -1e30f;
#pragma unroll
    for (int nt = 0; nt < 9; nt++) {
      int jl = nt * 16 + lm;
      bool valid =
          (jl == 128) ||
          (jl < 128 && jl >= qrow && jl <= qrow + 64 &&
           (unsigned)(qc0 - 32 + jl) < 1024u);
      sv[nt] = valid ? s[nt][r] * SCALE : -1e30f;
      mx = fmaxf(mx, sv[nt]);
    }
#pragma unroll
    for (int off = 1; off < 16; off <<= 1)
      mx = fmaxf(mx, __shfl_xor(mx, off, 16));
    float l = 0.f;
#pragma unroll
    for (int nt = 0; nt < 9; nt++) {
      float e = __expf(sv[nt] - mx);
      l += e;
      Ps[qrow * LDT + nt * 16 + lm] = f2h(e);
    }
#pragma unroll
    for (int off = 1; off < 16; off <<= 1) l += __shfl_xor(l, off, 16);
    L[r] = l;
  }
  __syncthreads();

  // ---- O = P·V : A=Ps rows (m=query), B=Vt rows (n=d), K=160 ----
  f32x4 oa[4];
#pragma unroll
  for (int nt = 0; nt < 4; nt++) oa[nt] = (f32x4){0.f, 0.f, 0.f, 0.f};
#pragma unroll
  for (int kc = 0; kc < 5; kc++) {
    f16x8 pa = *(const f16x8*)&Ps[(wv * 16 + lm) * LDT + kc * 32 + lq * 8];
#pragma unroll
    for (int nt = 0; nt < 4; nt++) {
      f16x8 vb = *(const f16x8*)&Vt[(nt * 16 + lm) * LDT + kc * 32 + lq * 8];
      oa[nt] = __builtin_amdgcn_mfma_f32_16x16x32_f16(pa, vb, oa[nt], 0, 0, 0);
    }
  }

  // ---- epilogue: normalize, write fp16 into Aatt[*, 512] ----
#pragma unroll
  for (int r = 0; r < 4; r++) {
    float inv = 1.f / L[r];
    int qrow = wv * 16 + lq * 4 + r;
    int pp = 2 * (qc0 + qrow) + par;
    unsigned short* ab = Aatt + ((size_t)b * S_LEN + 1 + pp) * 512 + h * 64;
#pragma unroll
    for (int nt = 0; nt < 4; nt++) ab[nt * 16 + lm] = f2h(oa[nt][r] * inv);
  }
}

// CLS attention, split-K stage 1 (fp16 qkv inputs).
__global__ __launch_bounds__(256) void cls_part_k(
    const unsigned short* __restrict__ qkv16, float* __restrict__ Pm,
    float* __restrict__ Pl, float* __restrict__ Po) {
  const int lane = threadIdx.x & 63;
  const int wv = threadIdx.x >> 6;
  const int ck = blockIdx.x;
  const int h = blockIdx.y;
  const int b = blockIdx.z;
  const unsigned short* base = qkv16 + (size_t)b * S_LEN * 1536;
  float qd = h2f(base[h * 64 + lane]) * SCALE;

  int c0 = ck * 64;
  int cend = (ck == 31) ? S_LEN : c0 + 64;

  float m = -1e30f, l = 0.f, o = 0.f;
  for (int j = c0 + wv; j < cend; j += 4) {
    const unsigned short* krow = base + (size_t)j * 1536 + 512 + h * 64;
    float kv = h2f(krow[lane]);
    float vv = h2f(krow[512 + lane]);
    float s = wave_sum64(qd * kv);
    float mn = fmaxf(m, s);
    float e0 = __expf(m - mn);
    float e1 = __expf(s - mn);
    l = l * e0 + e1;
    o = o * e0 + e1 * vv;
    m = mn;
  }

  __shared__ float sm[4], sl[4], so[4][64];
  if (lane == 0) {
    sm[wv] = m;
    sl[wv] = l;
  }
  so[wv][lane] = o;
  __syncthreads();
  if (wv == 0) {
    float M = -1e30f;
#pragma unroll
    for (int i = 0; i < 4; i++) M = fmaxf(M, sm[i]);
    float L = 0.f, O = 0.f;
#pragma unroll
    for (int i = 0; i < 4; i++) {
      float c = __expf(sm[i] - M);
      L += sl[i] * c;
      O += so[i][lane] * c;
    }
    int idx = (b * NH + h) * 32 + ck;
    if (lane == 0) {
      Pm[idx] = M;
      Pl[idx] = L;
    }
    Po[(size_t)idx * 64 + lane] = O;
  }
}

// CLS split-K stage 2: combine partials; write fp16 into Aatt row 0.
__global__ __launch_bounds__(64) void cls_comb_k(
    const float* __restrict__ Pm, const float* __restrict__ Pl,
    const float* __restrict__ Po, unsigned short* __restrict__ Aatt) {
  const int lane = threadIdx.x;
  const int h = blockIdx.x % NH;
  const int b = blockIdx.x / NH;
  float m = -1e30f, l = 0.f, o = 0.f;
  for (int ck = 0; ck < 32; ck++) {
    int idx = (b * NH + h) * 32 + ck;
    float mc = Pm[idx];
    float lc = Pl[idx];
    float oc = Po[(size_t)idx * 64 + lane];
    float mn = fmaxf(m, mc);
    float e0 = __expf(m - mn);
    float e1 = __expf(mc - mn);
    l = l * e0 + lc * e1;
    o = o * e0 + oc * e1;
    m = mn;
  }
  Aatt[(size_t)b * S_LEN * 512 + h * HD + lane] = f2h(o / l);
}

extern "C" void kernel_launch(void* const* d_in, const int* in_sizes, int n_in,
                              void* d_out, int out_size, void* d_ws,
                              size_t ws_size, hipStream_t stream) {
  const float* x = (const float*)d_in[0];
  const float* qkv_w = (const float*)d_in[1];
  const float* qkv_b = (const float*)d_in[2];
  const float* out_w = (const float*)d_in[3];
  const float* out_b = (const float*)d_in[4];
  float* out = (float*)d_out;

  const int M = 2 * S_LEN;  // 4098

  float* cls_pm = (float*)d_ws;                            // 512
  float* cls_pl = cls_pm + 512;                            // 512
  float* cls_po = cls_pl + 512;                            // 32768
  unsigned short* Xp = (unsigned short*)(cls_po + 32768);  // 4098*512 fp16
  unsigned short* Wq = Xp + (size_t)M * 512;               // 1536*512 fp16
  unsigned short* Wo = Wq + (size_t)1536 * 512;            // 512*512 fp16
  unsigned short* Aatt = Wo + (size_t)512 * 512;           // 4098*512 fp16
  unsigned short* qkv16 = Aatt + (size_t)M * 512;          // 4098*1536 fp16

  const int n0 = M * EMB;       // 2098176
  const int n1 = 1536 * EMB;    // 786432
  const int n2 = EMB * EMB;     // 262144
  int cvt_blocks = ((n0 + n1 + n2) / 8 + 255) / 256;
  cvt3_f16<<<cvt_blocks, 256, 0, stream>>>(x, Xp, n0, qkv_w, Wq, n1, out_w, Wo,
                                           n2);

  // QKV projection: fp16 GEMM K=512, fp16 output
  dim3 gq((M + 63) / 64, 1536 / 128);  // 65 x 12 = 780 blocks
  gemm_f16<64, 128, true><<<gq, 256, 0, stream>>>(Xp, Wq, qkv_b, qkv16, M,
                                                  1536, 512);

  cls_part_k<<<dim3(32, NH, 2), 256, 0, stream>>>(qkv16, cls_pm, cls_pl,
                                                  cls_po);
  cls_comb_k<<<2 * NH, 64, 0, stream>>>(cls_pm, cls_pl, cls_po, Aatt);
  patch_attn3<<<dim3(16, NH, 4), 256, 0, stream>>>(qkv16, Aatt);

  // Output projection: fp16 GEMM K=512, fp32 output
  dim3 go((M + 63) / 64, EMB / 64);  // 65 x 8 = 520 blocks
  gemm_f16<64, 64, false><<<go, 256, 0, stream>>>(Aatt, Wo, out_b, out, M, EMB,
                                                  512);
}